// Round 1
// baseline (3399.561 us; speedup 1.0000x reference)
//
#include <hip/hip_runtime.h>

#define N_NODES 100000
#define N_EDGES 1600000
#define F_IN    256
#define F_HID   128
#define F_OUT   16

// ---------------- degree / norm ----------------

__global__ __launch_bounds__(256) void k_deg_init(float* __restrict__ deg) {
    int i = blockIdx.x * 256 + threadIdx.x;
    if (i < N_NODES) deg[i] = 1.0f;   // self-loop
}

__global__ __launch_bounds__(256) void k_deg_accum(const int* __restrict__ col,
                                                   float* __restrict__ deg) {
    int e = blockIdx.x * 256 + threadIdx.x;
    if (e < N_EDGES) atomicAdd(&deg[col[e]], 1.0f);
}

__global__ __launch_bounds__(256) void k_dinv(float* __restrict__ deg) {
    int i = blockIdx.x * 256 + threadIdx.x;
    if (i < N_NODES) deg[i] = rsqrtf(deg[i]);   // deg >= 1 always
}

// ---------------- GEMM1: h1 = x @ W1  (100000x256 @ 256x128) ----------------
// 64-row tile per block, k-tiles of 32 staged in LDS.

__global__ __launch_bounds__(256) void k_gemm1(const float* __restrict__ x,
                                               const float* __restrict__ W1,
                                               float* __restrict__ h1) {
    __shared__ float xs[64 * 33];     // 64 rows x 32 k, pad 33
    __shared__ float ws[32 * 132];    // 32 k x 128 cols, pad 132
    const int tid = threadIdx.x;
    const int v0  = blockIdx.x * 64;
    const int r0  = (tid >> 4) * 4;       // 4 rows per thread
    const int c0  = (tid & 15) * 8;       // 8 cols per thread

    float acc[4][8];
    #pragma unroll
    for (int i = 0; i < 4; i++)
        #pragma unroll
        for (int j = 0; j < 8; j++) acc[i][j] = 0.0f;

    for (int kt = 0; kt < F_IN; kt += 32) {
        // stage x tile: 64x32 = 2048 floats, 8 per thread, coalesced
        #pragma unroll
        for (int i = 0; i < 8; i++) {
            int f = i * 256 + tid;
            int rr = f >> 5, kk = f & 31;
            int v = v0 + rr;
            int vc = v < N_NODES ? v : N_NODES - 1;   // clamp (stores guarded)
            xs[rr * 33 + kk] = x[vc * F_IN + kt + kk];
        }
        // stage W tile: 32x128 = 4096 floats, 16 per thread, coalesced
        #pragma unroll
        for (int i = 0; i < 16; i++) {
            int f = i * 256 + tid;
            int rr = f >> 7, cc = f & 127;
            ws[rr * 132 + cc] = W1[(kt + rr) * F_HID + cc];
        }
        __syncthreads();
        #pragma unroll
        for (int kk = 0; kk < 32; kk++) {
            float a[4], b[8];
            #pragma unroll
            for (int i = 0; i < 4; i++) a[i] = xs[(r0 + i) * 33 + kk];
            #pragma unroll
            for (int j = 0; j < 8; j++) b[j] = ws[kk * 132 + c0 + j];
            #pragma unroll
            for (int i = 0; i < 4; i++)
                #pragma unroll
                for (int j = 0; j < 8; j++)
                    acc[i][j] = fmaf(a[i], b[j], acc[i][j]);
        }
        __syncthreads();
    }
    #pragma unroll
    for (int i = 0; i < 4; i++) {
        int v = v0 + r0 + i;
        if (v < N_NODES) {
            #pragma unroll
            for (int j = 0; j < 8; j += 4) {
                float4 t = make_float4(acc[i][j], acc[i][j+1], acc[i][j+2], acc[i][j+3]);
                *(float4*)&h1[v * F_HID + c0 + j] = t;
            }
        }
    }
}

// ---------------- scatter-aggregate layer 1 ----------------
// one thread per (edge, float4-of-128): 32 threads/edge

__global__ __launch_bounds__(256) void k_scatter1(const int* __restrict__ rowi,
                                                  const int* __restrict__ coli,
                                                  const float* __restrict__ dinv,
                                                  const float* __restrict__ h1,
                                                  float* __restrict__ agg1) {
    long long gid = (long long)blockIdx.x * 256 + threadIdx.x;
    int e  = (int)(gid >> 5);
    int f4 = (int)(gid & 31);
    if (e >= N_EDGES) return;
    int r = rowi[e], c = coli[e];
    float w = dinv[r] * dinv[c];
    float4 hv = ((const float4*)h1)[r * 32 + f4];
    float* dst = &agg1[c * F_HID + f4 * 4];
    atomicAdd(dst + 0, w * hv.x);
    atomicAdd(dst + 1, w * hv.y);
    atomicAdd(dst + 2, w * hv.z);
    atomicAdd(dst + 3, w * hv.w);
}

__global__ __launch_bounds__(256) void k_self1(const float* __restrict__ dinv,
                                               const float* __restrict__ h1,
                                               float* __restrict__ agg1) {
    int gid = blockIdx.x * 256 + threadIdx.x;
    if (gid >= N_NODES * 32) return;
    int v = gid >> 5;
    float w = dinv[v] * dinv[v];
    float4 hv = ((const float4*)h1)[gid];
    float4 a  = ((const float4*)agg1)[gid];
    a.x += w * hv.x; a.y += w * hv.y; a.z += w * hv.z; a.w += w * hv.w;
    ((float4*)agg1)[gid] = a;
}

// ---------------- GEMM2: h2 = relu(agg1 + b1) @ W2  (100000x128 @ 128x16) ----

__global__ __launch_bounds__(256) void k_gemm2(const float* __restrict__ agg1,
                                               const float* __restrict__ b1,
                                               const float* __restrict__ W2,
                                               float* __restrict__ h2) {
    __shared__ float ls[64 * 129];    // 64 nodes x 128 feats, pad 129
    __shared__ float ws2[F_HID * F_OUT];
    __shared__ float b1s[F_HID];
    const int tid = threadIdx.x;
    const int v0  = blockIdx.x * 64;

    for (int i = tid; i < F_HID * F_OUT; i += 256) ws2[i] = W2[i];
    if (tid < F_HID) b1s[tid] = b1[tid];
    __syncthreads();

    // stage relu(agg1 + b1) tile: 64x128 = 8192 floats, 32 per thread
    #pragma unroll
    for (int i = 0; i < 32; i++) {
        int f = i * 256 + tid;
        int rr = f >> 7, cc = f & 127;
        int v = v0 + rr;
        float val = (v < N_NODES) ? agg1[v * F_HID + cc] : 0.0f;
        ls[rr * 129 + cc] = fmaxf(val + b1s[cc], 0.0f);
    }
    __syncthreads();

    const int v  = tid >> 2;          // 0..63
    const int cq = (tid & 3) * 4;     // 4 outputs per thread
    float acc[4] = {0.f, 0.f, 0.f, 0.f};
    #pragma unroll 8
    for (int f = 0; f < F_HID; f++) {
        float a = ls[v * 129 + f];
        #pragma unroll
        for (int j = 0; j < 4; j++)
            acc[j] = fmaf(a, ws2[f * F_OUT + cq + j], acc[j]);
    }
    int vv = v0 + v;
    if (vv < N_NODES) {
        float4 t = make_float4(acc[0], acc[1], acc[2], acc[3]);
        *(float4*)&h2[vv * F_OUT + cq] = t;
    }
}

// ---------------- output init + scatter-aggregate layer 2 ----------------

__global__ __launch_bounds__(256) void k_out_init(const float* __restrict__ b2,
                                                  float* __restrict__ out) {
    int gid = blockIdx.x * 256 + threadIdx.x;
    if (gid < N_NODES * F_OUT) out[gid] = b2[gid & 15];
}

__global__ __launch_bounds__(256) void k_scatter2(const int* __restrict__ rowi,
                                                  const int* __restrict__ coli,
                                                  const float* __restrict__ dinv,
                                                  const float* __restrict__ h2,
                                                  float* __restrict__ out) {
    int gid = blockIdx.x * 256 + threadIdx.x;
    int e = gid >> 2, q = gid & 3;
    if (e >= N_EDGES) return;
    int r = rowi[e], c = coli[e];
    float w = dinv[r] * dinv[c];
    float4 hv = ((const float4*)h2)[r * 4 + q];
    float* dst = &out[c * F_OUT + q * 4];
    atomicAdd(dst + 0, w * hv.x);
    atomicAdd(dst + 1, w * hv.y);
    atomicAdd(dst + 2, w * hv.z);
    atomicAdd(dst + 3, w * hv.w);
}

__global__ __launch_bounds__(256) void k_self2(const float* __restrict__ dinv,
                                               const float* __restrict__ h2,
                                               float* __restrict__ out) {
    int gid = blockIdx.x * 256 + threadIdx.x;
    if (gid >= N_NODES * 4) return;
    int v = gid >> 2;
    float w = dinv[v] * dinv[v];
    float4 hv = ((const float4*)h2)[gid];
    float4 a  = ((const float4*)out)[gid];
    a.x += w * hv.x; a.y += w * hv.y; a.z += w * hv.z; a.w += w * hv.w;
    ((float4*)out)[gid] = a;
}

// ---------------- launch ----------------

extern "C" void kernel_launch(void* const* d_in, const int* in_sizes, int n_in,
                              void* d_out, int out_size, void* d_ws, size_t ws_size,
                              hipStream_t stream) {
    const float* x   = (const float*)d_in[0];
    const int*   ei  = (const int*)d_in[1];       // int32 per harness convention
    const float* W1  = (const float*)d_in[2];
    const float* b1  = (const float*)d_in[3];
    const float* W2  = (const float*)d_in[4];
    const float* b2  = (const float*)d_in[5];
    float* out = (float*)d_out;

    const int* rowi = ei;             // edge_index[0] = source
    const int* coli = ei + N_EDGES;   // edge_index[1] = target

    char* ws = (char*)d_ws;
    float* dinv = (float*)(ws + 0);                       // 400 KB
    float* h1   = (float*)(ws + 524288);                  // 51.2 MB
    float* agg1 = (float*)(ws + 52428800);                // 51.2 MB
    float* h2   = (float*)(ws + 104857600);               // 6.4 MB

    hipMemsetAsync(agg1, 0, (size_t)N_NODES * F_HID * sizeof(float), stream);

    k_deg_init <<<(N_NODES + 255) / 256, 256, 0, stream>>>(dinv);
    k_deg_accum<<<(N_EDGES + 255) / 256, 256, 0, stream>>>(coli, dinv);
    k_dinv     <<<(N_NODES + 255) / 256, 256, 0, stream>>>(dinv);

    k_gemm1    <<<(N_NODES + 63) / 64, 256, 0, stream>>>(x, W1, h1);

    k_scatter1 <<<(N_EDGES * 32 + 255) / 256, 256, 0, stream>>>(rowi, coli, dinv, h1, agg1);
    k_self1    <<<(N_NODES * 32 + 255) / 256, 256, 0, stream>>>(dinv, h1, agg1);

    k_gemm2    <<<(N_NODES + 63) / 64, 256, 0, stream>>>(agg1, b1, W2, h2);

    k_out_init <<<(N_NODES * 16 + 255) / 256, 256, 0, stream>>>(b2, out);
    k_scatter2 <<<(N_EDGES * 4 + 255) / 256, 256, 0, stream>>>(rowi, coli, dinv, h2, out);
    k_self2    <<<(N_NODES * 4 + 255) / 256, 256, 0, stream>>>(dinv, h2, out);
}

// Round 2
// 633.763 us; speedup vs baseline: 5.3641x; 5.3641x over previous
//
#include <hip/hip_runtime.h>

#define N_NODES 100000
#define N_EDGES 1600000
#define F_IN    256
#define F_HID   128
#define F_OUT   16
#define SCAN_BLOCKS ((N_NODES + 1023) / 1024)   // 98

// ======================= CSR build =======================

__global__ __launch_bounds__(256) void k_hist(const int* __restrict__ col,
                                              int* __restrict__ cnt) {
    int e = blockIdx.x * 256 + threadIdx.x;
    if (e < N_EDGES) atomicAdd(&cnt[col[e]], 1);
}

// per-block sums of 1024-elem chunks
__global__ __launch_bounds__(256) void k_scan_partial(const int* __restrict__ cnt,
                                                      int* __restrict__ bsum) {
    __shared__ int sd[256];
    int t = threadIdx.x;
    int base = blockIdx.x * 1024 + t * 4;
    int s = 0;
    #pragma unroll
    for (int i = 0; i < 4; i++) {
        int idx = base + i;
        if (idx < N_NODES) s += cnt[idx];
    }
    sd[t] = s; __syncthreads();
    for (int off = 128; off > 0; off >>= 1) {
        if (t < off) sd[t] += sd[t + off];
        __syncthreads();
    }
    if (t == 0) bsum[blockIdx.x] = sd[0];
}

// exclusive scan of the 98 block sums (single block)
__global__ __launch_bounds__(128) void k_scan_top(int* __restrict__ bsum,
                                                  int* __restrict__ row_ptr) {
    __shared__ int sd[128];
    int t = threadIdx.x;
    int v = (t < SCAN_BLOCKS) ? bsum[t] : 0;
    sd[t] = v; __syncthreads();
    for (int off = 1; off < 128; off <<= 1) {
        int x = (t >= off) ? sd[t - off] : 0;
        __syncthreads();
        sd[t] += x;
        __syncthreads();
    }
    if (t < SCAN_BLOCKS) bsum[t] = sd[t] - v;       // exclusive
    if (t == SCAN_BLOCKS - 1) row_ptr[N_NODES] = sd[t];  // total = N_EDGES
}

__global__ __launch_bounds__(256) void k_scan_final(const int* __restrict__ cnt,
                                                    const int* __restrict__ bsum,
                                                    int* __restrict__ row_ptr) {
    __shared__ int sd[256];
    int t = threadIdx.x;
    int base = blockIdx.x * 1024 + t * 4;
    int v[4]; int s = 0;
    #pragma unroll
    for (int i = 0; i < 4; i++) {
        int idx = base + i;
        v[i] = (idx < N_NODES) ? cnt[idx] : 0;
        s += v[i];
    }
    sd[t] = s; __syncthreads();
    for (int off = 1; off < 256; off <<= 1) {
        int x = (t >= off) ? sd[t - off] : 0;
        __syncthreads();
        sd[t] += x;
        __syncthreads();
    }
    int excl = sd[t] - s + bsum[blockIdx.x];
    #pragma unroll
    for (int i = 0; i < 4; i++) {
        int idx = base + i;
        if (idx < N_NODES) row_ptr[idx] = excl;
        excl += v[i];
    }
}

__global__ __launch_bounds__(256) void k_dinv(const int* __restrict__ cnt,
                                              float* __restrict__ dinv) {
    int i = blockIdx.x * 256 + threadIdx.x;
    if (i < N_NODES) dinv[i] = rsqrtf(1.0f + (float)cnt[i]);  // +1 self-loop
}

__global__ __launch_bounds__(256) void k_copy_ptr(const int* __restrict__ row_ptr,
                                                  int* __restrict__ next) {
    int i = blockIdx.x * 256 + threadIdx.x;
    if (i < N_NODES) next[i] = row_ptr[i];
}

__global__ __launch_bounds__(256) void k_fill(const int* __restrict__ rowi,
                                              const int* __restrict__ coli,
                                              int* __restrict__ next,
                                              int* __restrict__ esrc) {
    int e = blockIdx.x * 256 + threadIdx.x;
    if (e < N_EDGES) {
        int p = atomicAdd(&next[coli[e]], 1);
        esrc[p] = rowi[e];
    }
}

// ============ GEMM1: g1 = dinv * (x @ W1)  [100000x256 @ 256x128] ============

__global__ __launch_bounds__(256) void k_gemm1(const float* __restrict__ x,
                                               const float* __restrict__ W1,
                                               const float* __restrict__ dinv,
                                               float* __restrict__ g1) {
    __shared__ float xs[64 * 33];
    __shared__ float ws[32 * 132];
    const int tid = threadIdx.x;
    const int v0  = blockIdx.x * 64;
    const int r0  = (tid >> 4) * 4;
    const int c0  = (tid & 15) * 8;

    float acc[4][8];
    #pragma unroll
    for (int i = 0; i < 4; i++)
        #pragma unroll
        for (int j = 0; j < 8; j++) acc[i][j] = 0.0f;

    for (int kt = 0; kt < F_IN; kt += 32) {
        #pragma unroll
        for (int i = 0; i < 8; i++) {
            int f = i * 256 + tid;
            int rr = f >> 5, kk = f & 31;
            int v = v0 + rr;
            int vc = v < N_NODES ? v : N_NODES - 1;
            xs[rr * 33 + kk] = x[vc * F_IN + kt + kk];
        }
        #pragma unroll
        for (int i = 0; i < 16; i++) {
            int f = i * 256 + tid;
            int rr = f >> 7, cc = f & 127;
            ws[rr * 132 + cc] = W1[(kt + rr) * F_HID + cc];
        }
        __syncthreads();
        #pragma unroll
        for (int kk = 0; kk < 32; kk++) {
            float a[4], b[8];
            #pragma unroll
            for (int i = 0; i < 4; i++) a[i] = xs[(r0 + i) * 33 + kk];
            #pragma unroll
            for (int j = 0; j < 8; j++) b[j] = ws[kk * 132 + c0 + j];
            #pragma unroll
            for (int i = 0; i < 4; i++)
                #pragma unroll
                for (int j = 0; j < 8; j++)
                    acc[i][j] = fmaf(a[i], b[j], acc[i][j]);
        }
        __syncthreads();
    }
    #pragma unroll
    for (int i = 0; i < 4; i++) {
        int v = v0 + r0 + i;
        if (v < N_NODES) {
            float w = dinv[v];
            #pragma unroll
            for (int j = 0; j < 8; j += 4) {
                float4 t = make_float4(w*acc[i][j], w*acc[i][j+1], w*acc[i][j+2], w*acc[i][j+3]);
                *(float4*)&g1[v * F_HID + c0 + j] = t;
            }
        }
    }
}

// ============ aggregate layer 1 (gather, wave per node) ============
// h1b[c] = relu( dinv[c] * (sum_{e->c} g1[src] + g1[c]) + b1 )

__global__ __launch_bounds__(256) void k_agg1(const int* __restrict__ row_ptr,
                                              const int* __restrict__ esrc,
                                              const float* __restrict__ dinv,
                                              const float* __restrict__ g1,
                                              const float* __restrict__ b1,
                                              float* __restrict__ h1b) {
    int node = blockIdx.x * 4 + (threadIdx.x >> 6);
    int lane = threadIdx.x & 63;
    if (node >= N_NODES) return;
    const float2* G = (const float2*)g1;
    int s = row_ptr[node], t = row_ptr[node + 1];
    float2 acc = G[node * 64 + lane];          // self-loop term g1[c]
    int e = s;
    for (; e + 1 < t; e += 2) {
        int r0 = esrc[e], r1 = esrc[e + 1];
        float2 a = G[r0 * 64 + lane];
        float2 b = G[r1 * 64 + lane];
        acc.x += a.x + b.x;
        acc.y += a.y + b.y;
    }
    if (e < t) {
        int r = esrc[e];
        float2 a = G[r * 64 + lane];
        acc.x += a.x; acc.y += a.y;
    }
    float w = dinv[node];
    float2 bb = ((const float2*)b1)[lane];
    float2 o;
    o.x = fmaxf(fmaf(w, acc.x, bb.x), 0.0f);
    o.y = fmaxf(fmaf(w, acc.y, bb.y), 0.0f);
    ((float2*)h1b)[node * 64 + lane] = o;
}

// ============ GEMM2: g2 = dinv * (h1b @ W2)  [100000x128 @ 128x16] ============

__global__ __launch_bounds__(256) void k_gemm2(const float* __restrict__ h1b,
                                               const float* __restrict__ W2,
                                               const float* __restrict__ dinv,
                                               float* __restrict__ g2) {
    __shared__ float ls[64 * 129];
    __shared__ float ws2[F_HID * F_OUT];
    const int tid = threadIdx.x;
    const int v0  = blockIdx.x * 64;

    for (int i = tid; i < F_HID * F_OUT; i += 256) ws2[i] = W2[i];
    __syncthreads();

    #pragma unroll
    for (int i = 0; i < 32; i++) {
        int f = i * 256 + tid;
        int rr = f >> 7, cc = f & 127;
        int v = v0 + rr;
        ls[rr * 129 + cc] = (v < N_NODES) ? h1b[v * F_HID + cc] : 0.0f;
    }
    __syncthreads();

    const int v  = tid >> 2;
    const int cq = (tid & 3) * 4;
    float acc[4] = {0.f, 0.f, 0.f, 0.f};
    #pragma unroll 8
    for (int f = 0; f < F_HID; f++) {
        float a = ls[v * 129 + f];
        #pragma unroll
        for (int j = 0; j < 4; j++)
            acc[j] = fmaf(a, ws2[f * F_OUT + cq + j], acc[j]);
    }
    int vv = v0 + v;
    if (vv < N_NODES) {
        float w = dinv[vv];
        float4 t = make_float4(w*acc[0], w*acc[1], w*acc[2], w*acc[3]);
        *(float4*)&g2[vv * F_OUT + cq] = t;
    }
}

// ============ aggregate layer 2 (gather, 16 lanes per node) ============
// out[c] = dinv[c] * (sum g2[src] + g2[c]) + b2

__global__ __launch_bounds__(256) void k_agg2(const int* __restrict__ row_ptr,
                                              const int* __restrict__ esrc,
                                              const float* __restrict__ dinv,
                                              const float* __restrict__ g2,
                                              const float* __restrict__ b2,
                                              float* __restrict__ out) {
    int gid = blockIdx.x * 256 + threadIdx.x;
    int node = gid >> 4;
    int f = gid & 15;
    if (node >= N_NODES) return;
    int s = row_ptr[node], t = row_ptr[node + 1];
    float acc = g2[node * 16 + f];             // self-loop
    int e = s;
    for (; e + 1 < t; e += 2) {
        int r0 = esrc[e], r1 = esrc[e + 1];
        acc += g2[r0 * 16 + f] + g2[r1 * 16 + f];
    }
    if (e < t) acc += g2[esrc[e] * 16 + f];
    out[node * 16 + f] = fmaf(dinv[node], acc, b2[f]);
}

// ======================= launch =======================

extern "C" void kernel_launch(void* const* d_in, const int* in_sizes, int n_in,
                              void* d_out, int out_size, void* d_ws, size_t ws_size,
                              hipStream_t stream) {
    const float* x   = (const float*)d_in[0];
    const int*   ei  = (const int*)d_in[1];
    const float* W1  = (const float*)d_in[2];
    const float* b1  = (const float*)d_in[3];
    const float* W2  = (const float*)d_in[4];
    const float* b2  = (const float*)d_in[5];
    float* out = (float*)d_out;

    const int* rowi = ei;             // sources
    const int* coli = ei + N_EDGES;   // targets

    char* ws = (char*)d_ws;
    int*   cnt     = (int*)(ws + 0);             // 400 KB (reused as `next`)
    int*   row_ptr = (int*)(ws + 524288);        // 400 KB (+4)
    float* dinv    = (float*)(ws + 1048576);     // 400 KB
    int*   bsum    = (int*)(ws + 1572864);       // tiny
    int*   esrc    = (int*)(ws + 2097152);       // 6.4 MB
    float* g1      = (float*)(ws + 8808448);     // 51.2 MB
    float* h1b     = (float*)(ws + 60008448);    // 51.2 MB
    float* g2      = (float*)(ws + 8808448);     // reuses g1 (dead after agg1)

    hipMemsetAsync(cnt, 0, N_NODES * sizeof(int), stream);

    k_hist        <<<(N_EDGES + 255) / 256, 256, 0, stream>>>(coli, cnt);
    k_scan_partial<<<SCAN_BLOCKS, 256, 0, stream>>>(cnt, bsum);
    k_scan_top    <<<1, 128, 0, stream>>>(bsum, row_ptr);
    k_scan_final  <<<SCAN_BLOCKS, 256, 0, stream>>>(cnt, bsum, row_ptr);
    k_dinv        <<<(N_NODES + 255) / 256, 256, 0, stream>>>(cnt, dinv);
    k_copy_ptr    <<<(N_NODES + 255) / 256, 256, 0, stream>>>(row_ptr, cnt); // cnt = next
    k_fill        <<<(N_EDGES + 255) / 256, 256, 0, stream>>>(rowi, coli, cnt, esrc);

    k_gemm1       <<<(N_NODES + 63) / 64, 256, 0, stream>>>(x, W1, dinv, g1);
    k_agg1        <<<(N_NODES + 3) / 4, 256, 0, stream>>>(row_ptr, esrc, dinv, g1, b1, h1b);
    k_gemm2       <<<(N_NODES + 63) / 64, 256, 0, stream>>>(h1b, W2, dinv, g2);
    k_agg2        <<<(N_NODES * 16 + 255) / 256, 256, 0, stream>>>(row_ptr, esrc, dinv, g2, b2, out);
}

// Round 3
// 553.758 us; speedup vs baseline: 6.1391x; 1.1445x over previous
//
#include <hip/hip_runtime.h>

#define N_NODES 100000
#define N_EDGES 1600000
#define F_IN    256
#define F_HID   128
#define F_OUT   16
#define SCAN_BLOCKS 98   // ceil(100000/1024)

typedef __attribute__((ext_vector_type(8))) short short8;
typedef __attribute__((ext_vector_type(4))) float float4v;

__device__ __forceinline__ unsigned int bf16_rn(float f) {
    unsigned int u = __float_as_uint(f);
    return (u + 0x7FFFu + ((u >> 16) & 1u)) >> 16;
}
__device__ __forceinline__ unsigned int pk2(float lo, float hi) {
    return bf16_rn(lo) | (bf16_rn(hi) << 16);
}

// ======================= CSR build =======================

__global__ __launch_bounds__(256) void k_hist(const int* __restrict__ col,
                                              int* __restrict__ cnt) {
    int e = blockIdx.x * 256 + threadIdx.x;
    if (e < N_EDGES) atomicAdd(&cnt[col[e]], 1);
}

__global__ __launch_bounds__(256) void k_scan_partial(const int* __restrict__ cnt,
                                                      int* __restrict__ bsum) {
    __shared__ int sd[256];
    int t = threadIdx.x;
    int base = blockIdx.x * 1024 + t * 4;
    int s = 0;
    #pragma unroll
    for (int i = 0; i < 4; i++) {
        int idx = base + i;
        if (idx < N_NODES) s += cnt[idx];
    }
    sd[t] = s; __syncthreads();
    for (int off = 128; off > 0; off >>= 1) {
        if (t < off) sd[t] += sd[t + off];
        __syncthreads();
    }
    if (t == 0) bsum[blockIdx.x] = sd[0];
}

__global__ __launch_bounds__(128) void k_scan_top(int* __restrict__ bsum,
                                                  int* __restrict__ row_ptr) {
    __shared__ int sd[128];
    int t = threadIdx.x;
    int v = (t < SCAN_BLOCKS) ? bsum[t] : 0;
    sd[t] = v; __syncthreads();
    for (int off = 1; off < 128; off <<= 1) {
        int x = (t >= off) ? sd[t - off] : 0;
        __syncthreads();
        sd[t] += x;
        __syncthreads();
    }
    if (t < SCAN_BLOCKS) bsum[t] = sd[t] - v;            // exclusive
    if (t == SCAN_BLOCKS - 1) row_ptr[N_NODES] = sd[t];  // total
}

// + fused: writes row_ptr, next (=cnt buffer), dinv
__global__ __launch_bounds__(256) void k_scan_final(int* __restrict__ cnt,
                                                    const int* __restrict__ bsum,
                                                    int* __restrict__ row_ptr,
                                                    float* __restrict__ dinv) {
    __shared__ int sd[256];
    int t = threadIdx.x;
    int base = blockIdx.x * 1024 + t * 4;
    int v[4]; int s = 0;
    #pragma unroll
    for (int i = 0; i < 4; i++) {
        int idx = base + i;
        v[i] = (idx < N_NODES) ? cnt[idx] : 0;
        s += v[i];
    }
    sd[t] = s; __syncthreads();
    for (int off = 1; off < 256; off <<= 1) {
        int x = (t >= off) ? sd[t - off] : 0;
        __syncthreads();
        sd[t] += x;
        __syncthreads();
    }
    int excl = sd[t] - s + bsum[blockIdx.x];
    #pragma unroll
    for (int i = 0; i < 4; i++) {
        int idx = base + i;
        if (idx < N_NODES) {
            row_ptr[idx] = excl;
            cnt[idx] = excl;                       // becomes `next`
            dinv[idx] = rsqrtf(1.0f + (float)v[i]);
        }
        excl += v[i];
    }
}

__global__ __launch_bounds__(256) void k_fill(const int* __restrict__ rowi,
                                              const int* __restrict__ coli,
                                              int* __restrict__ next,
                                              int* __restrict__ esrc) {
    int e = blockIdx.x * 256 + threadIdx.x;
    if (e < N_EDGES) {
        int p = atomicAdd(&next[coli[e]], 1);
        esrc[p] = rowi[e];
    }
}

// ============ W1 -> bf16 transposed Wt[col][k] ============

__global__ __launch_bounds__(256) void k_transW(const float* __restrict__ W1,
                                                ushort* __restrict__ Wt) {
    int t = blockIdx.x * 256 + threadIdx.x;   // 32768
    int c = t & 127, k = t >> 7;
    Wt[c * 256 + k] = (ushort)bf16_rn(W1[k * 128 + c]);
}

// ============ GEMM1 (MFMA bf16): g1 = bf16(dinv * (x @ W1)) ============
// block: 256 thr (4 waves), 128 rows x 128 cols, K=256 in 8 steps of 32

__global__ __launch_bounds__(256) void k_gemm1(const float* __restrict__ x,
                                               const ushort* __restrict__ Wt,
                                               const float* __restrict__ dinv,
                                               ushort* __restrict__ g1) {
    __shared__ ushort Al[128 * 40];   // rows x 32k, stride 40 (80B, conflict-free)
    __shared__ ushort Bl[128 * 40];   // cols x 32k
    const int tid = threadIdx.x;
    const int w = tid >> 6;
    const int l = tid & 63;
    const int m = l & 15;       // MFMA m/n index
    const int q = l >> 4;       // quad -> k-group / row-group
    const int R0 = blockIdx.x * 128;

    const int srow = tid >> 1;          // staging row / col
    const int soff = (tid & 1) * 16;    // k half

    int vr = R0 + srow; if (vr > N_NODES - 1) vr = N_NODES - 1;
    const float*  xrow = &x[(size_t)vr * F_IN + soff];
    const ushort* wrow = &Wt[srow * 256 + soff];

    float4v acc[2][8];
    #pragma unroll
    for (int i = 0; i < 2; i++)
        #pragma unroll
        for (int j = 0; j < 8; j++) acc[i][j] = (float4v){0.f, 0.f, 0.f, 0.f};

    for (int kt = 0; kt < F_IN; kt += 32) {
        float4 f0 = *(const float4*)&xrow[kt + 0];
        float4 f1 = *(const float4*)&xrow[kt + 4];
        float4 f2 = *(const float4*)&xrow[kt + 8];
        float4 f3 = *(const float4*)&xrow[kt + 12];
        uint4 wv0 = *(const uint4*)&wrow[kt + 0];
        uint4 wv1 = *(const uint4*)&wrow[kt + 8];
        uint4 pa, pb;
        pa.x = pk2(f0.x, f0.y); pa.y = pk2(f0.z, f0.w);
        pa.z = pk2(f1.x, f1.y); pa.w = pk2(f1.z, f1.w);
        pb.x = pk2(f2.x, f2.y); pb.y = pk2(f2.z, f2.w);
        pb.z = pk2(f3.x, f3.y); pb.w = pk2(f3.z, f3.w);
        *(uint4*)&Al[srow * 40 + soff]     = pa;
        *(uint4*)&Al[srow * 40 + soff + 8] = pb;
        *(uint4*)&Bl[srow * 40 + soff]     = wv0;
        *(uint4*)&Bl[srow * 40 + soff + 8] = wv1;
        __syncthreads();

        short8 af0 = *(const short8*)&Al[(w * 32 + m) * 40 + q * 8];
        short8 af1 = *(const short8*)&Al[(w * 32 + 16 + m) * 40 + q * 8];
        #pragma unroll
        for (int n = 0; n < 8; n++) {
            short8 bfr = *(const short8*)&Bl[(n * 16 + m) * 40 + q * 8];
            acc[0][n] = __builtin_amdgcn_mfma_f32_16x16x32_bf16(af0, bfr, acc[0][n], 0, 0, 0);
            acc[1][n] = __builtin_amdgcn_mfma_f32_16x16x32_bf16(af1, bfr, acc[1][n], 0, 0, 0);
        }
        __syncthreads();
    }

    // epilogue: C/D layout col=m, row=q*4+reg
    const int rbase = R0 + w * 32 + q * 4;
    float dv0[4], dv1[4];
    #pragma unroll
    for (int r = 0; r < 4; r++) {
        int v0 = rbase + r;      dv0[r] = (v0 < N_NODES) ? dinv[v0] : 0.f;
        int v1 = rbase + 16 + r; dv1[r] = (v1 < N_NODES) ? dinv[v1] : 0.f;
    }
    #pragma unroll
    for (int n = 0; n < 8; n++) {
        #pragma unroll
        for (int r = 0; r < 4; r++) {
            int v0 = rbase + r;
            if (v0 < N_NODES)
                g1[v0 * F_HID + n * 16 + m] = (ushort)bf16_rn(dv0[r] * acc[0][n][r]);
            int v1 = rbase + 16 + r;
            if (v1 < N_NODES)
                g1[v1 * F_HID + n * 16 + m] = (ushort)bf16_rn(dv1[r] * acc[1][n][r]);
        }
    }
}

// ============ aggregate layer 1 (gather, wave/node, bf16 g1) ============

__global__ __launch_bounds__(256) void k_agg1(const int* __restrict__ row_ptr,
                                              const int* __restrict__ esrc,
                                              const float* __restrict__ dinv,
                                              const unsigned int* __restrict__ g1, // bf16 pairs
                                              const float* __restrict__ b1,
                                              float* __restrict__ h1b) {
    int node = blockIdx.x * 4 + (threadIdx.x >> 6);
    int lane = threadIdx.x & 63;
    if (node >= N_NODES) return;
    int s = row_ptr[node], t = row_ptr[node + 1];
    unsigned int u = g1[node * 64 + lane];     // self-loop
    float ax = __uint_as_float(u << 16);
    float ay = __uint_as_float(u & 0xFFFF0000u);
    int e = s;
    for (; e + 1 < t; e += 2) {
        unsigned int u0 = g1[esrc[e] * 64 + lane];
        unsigned int u1 = g1[esrc[e + 1] * 64 + lane];
        ax += __uint_as_float(u0 << 16) + __uint_as_float(u1 << 16);
        ay += __uint_as_float(u0 & 0xFFFF0000u) + __uint_as_float(u1 & 0xFFFF0000u);
    }
    if (e < t) {
        unsigned int u0 = g1[esrc[e] * 64 + lane];
        ax += __uint_as_float(u0 << 16);
        ay += __uint_as_float(u0 & 0xFFFF0000u);
    }
    float wv = dinv[node];
    float2 bb = ((const float2*)b1)[lane];
    float2 o;
    o.x = fmaxf(fmaf(wv, ax, bb.x), 0.0f);
    o.y = fmaxf(fmaf(wv, ay, bb.y), 0.0f);
    ((float2*)h1b)[node * 64 + lane] = o;
}

// ============ GEMM2: g2 = dinv * (h1b @ W2) ============

__global__ __launch_bounds__(256) void k_gemm2(const float* __restrict__ h1b,
                                               const float* __restrict__ W2,
                                               const float* __restrict__ dinv,
                                               float* __restrict__ g2) {
    __shared__ float ls[64 * 129];
    __shared__ float ws2[F_HID * F_OUT];
    const int tid = threadIdx.x;
    const int v0  = blockIdx.x * 64;

    for (int i = tid; i < F_HID * F_OUT; i += 256) ws2[i] = W2[i];
    __syncthreads();

    #pragma unroll
    for (int i = 0; i < 32; i++) {
        int f = i * 256 + tid;
        int rr = f >> 7, cc = f & 127;
        int v = v0 + rr;
        ls[rr * 129 + cc] = (v < N_NODES) ? h1b[v * F_HID + cc] : 0.0f;
    }
    __syncthreads();

    const int v  = tid >> 2;
    const int cq = (tid & 3) * 4;
    float acc[4] = {0.f, 0.f, 0.f, 0.f};
    #pragma unroll 8
    for (int f = 0; f < F_HID; f++) {
        float a = ls[v * 129 + f];
        #pragma unroll
        for (int j = 0; j < 4; j++)
            acc[j] = fmaf(a, ws2[f * F_OUT + cq + j], acc[j]);
    }
    int vv = v0 + v;
    if (vv < N_NODES) {
        float w = dinv[vv];
        float4 t = make_float4(w * acc[0], w * acc[1], w * acc[2], w * acc[3]);
        *(float4*)&g2[vv * F_OUT + cq] = t;
    }
}

// ============ aggregate layer 2 ============

__global__ __launch_bounds__(256) void k_agg2(const int* __restrict__ row_ptr,
                                              const int* __restrict__ esrc,
                                              const float* __restrict__ dinv,
                                              const float* __restrict__ g2,
                                              const float* __restrict__ b2,
                                              float* __restrict__ out) {
    int gid = blockIdx.x * 256 + threadIdx.x;
    int node = gid >> 4;
    int f = gid & 15;
    if (node >= N_NODES) return;
    int s = row_ptr[node], t = row_ptr[node + 1];
    float acc = g2[node * 16 + f];
    int e = s;
    for (; e + 1 < t; e += 2) {
        acc += g2[esrc[e] * 16 + f] + g2[esrc[e + 1] * 16 + f];
    }
    if (e < t) acc += g2[esrc[e] * 16 + f];
    out[node * 16 + f] = fmaf(dinv[node], acc, b2[f]);
}

// ======================= launch =======================

extern "C" void kernel_launch(void* const* d_in, const int* in_sizes, int n_in,
                              void* d_out, int out_size, void* d_ws, size_t ws_size,
                              hipStream_t stream) {
    const float* x   = (const float*)d_in[0];
    const int*   ei  = (const int*)d_in[1];
    const float* W1  = (const float*)d_in[2];
    const float* b1  = (const float*)d_in[3];
    const float* W2  = (const float*)d_in[4];
    const float* b2  = (const float*)d_in[5];
    float* out = (float*)d_out;

    const int* rowi = ei;
    const int* coli = ei + N_EDGES;

    char* ws = (char*)d_ws;
    int*    cnt     = (int*)(ws + 0);            // 400KB, reused as `next`
    int*    row_ptr = (int*)(ws + 524288);
    float*  dinv    = (float*)(ws + 1048576);
    int*    bsum    = (int*)(ws + 1572864);
    int*    esrc    = (int*)(ws + 2097152);      // 6.4 MB
    ushort* Wt      = (ushort*)(ws + 8519680);   // 64 KB bf16 W1^T
    ushort* g1      = (ushort*)(ws + 8650752);   // 25.6 MB bf16
    float*  g2      = (float*)(ws + 8650752);    // reuses g1 (dead after agg1)
    float*  h1b     = (float*)(ws + 34603008);   // 51.2 MB

    hipMemsetAsync(cnt, 0, N_NODES * sizeof(int), stream);

    k_hist        <<<(N_EDGES + 255) / 256, 256, 0, stream>>>(coli, cnt);
    k_scan_partial<<<SCAN_BLOCKS, 256, 0, stream>>>(cnt, bsum);
    k_scan_top    <<<1, 128, 0, stream>>>(bsum, row_ptr);
    k_scan_final  <<<SCAN_BLOCKS, 256, 0, stream>>>(cnt, bsum, row_ptr, dinv);
    k_fill        <<<(N_EDGES + 255) / 256, 256, 0, stream>>>(rowi, coli, cnt, esrc);
    k_transW      <<<128, 256, 0, stream>>>(W1, Wt);

    k_gemm1       <<<(N_NODES + 127) / 128, 256, 0, stream>>>(x, Wt, dinv, g1);
    k_agg1        <<<(N_NODES + 3) / 4, 256, 0, stream>>>(row_ptr, esrc, dinv,
                                                          (const unsigned int*)g1, b1, h1b);
    k_gemm2       <<<(N_NODES + 63) / 64, 256, 0, stream>>>(h1b, W2, dinv, g2);
    k_agg2        <<<(N_NODES * 16 + 255) / 256, 256, 0, stream>>>(row_ptr, esrc, dinv, g2, b2, out);
}

// Round 4
// 544.963 us; speedup vs baseline: 6.2381x; 1.0161x over previous
//
#include <hip/hip_runtime.h>

#define N_NODES 100000
#define N_EDGES 1600000
#define F_IN    256
#define F_HID   128
#define F_OUT   16
#define SCAN_BLOCKS 98   // ceil(100000/1024)

typedef __attribute__((ext_vector_type(8))) short short8;
typedef __attribute__((ext_vector_type(4))) float float4v;

__device__ __forceinline__ unsigned int bf16_rn(float f) {
    unsigned int u = __float_as_uint(f);
    return (u + 0x7FFFu + ((u >> 16) & 1u)) >> 16;
}
__device__ __forceinline__ unsigned int pk2(float lo, float hi) {
    return bf16_rn(lo) | (bf16_rn(hi) << 16);
}

// ======================= CSR build =======================

__global__ __launch_bounds__(256) void k_hist(const int* __restrict__ col,
                                              int* __restrict__ cnt) {
    int e = blockIdx.x * 256 + threadIdx.x;
    if (e < N_EDGES) atomicAdd(&cnt[col[e]], 1);
}

__global__ __launch_bounds__(256) void k_scan_partial(const int* __restrict__ cnt,
                                                      int* __restrict__ bsum) {
    __shared__ int sd[256];
    int t = threadIdx.x;
    int base = blockIdx.x * 1024 + t * 4;
    int s = 0;
    #pragma unroll
    for (int i = 0; i < 4; i++) {
        int idx = base + i;
        if (idx < N_NODES) s += cnt[idx];
    }
    sd[t] = s; __syncthreads();
    for (int off = 128; off > 0; off >>= 1) {
        if (t < off) sd[t] += sd[t + off];
        __syncthreads();
    }
    if (t == 0) bsum[blockIdx.x] = sd[0];
}

__global__ __launch_bounds__(128) void k_scan_top(int* __restrict__ bsum,
                                                  int* __restrict__ row_ptr) {
    __shared__ int sd[128];
    int t = threadIdx.x;
    int v = (t < SCAN_BLOCKS) ? bsum[t] : 0;
    sd[t] = v; __syncthreads();
    for (int off = 1; off < 128; off <<= 1) {
        int x = (t >= off) ? sd[t - off] : 0;
        __syncthreads();
        sd[t] += x;
        __syncthreads();
    }
    if (t < SCAN_BLOCKS) bsum[t] = sd[t] - v;            // exclusive
    if (t == SCAN_BLOCKS - 1) row_ptr[N_NODES] = sd[t];  // total
}

// fused: writes row_ptr, next (=cnt buffer), dinv
__global__ __launch_bounds__(256) void k_scan_final(int* __restrict__ cnt,
                                                    const int* __restrict__ bsum,
                                                    int* __restrict__ row_ptr,
                                                    float* __restrict__ dinv) {
    __shared__ int sd[256];
    int t = threadIdx.x;
    int base = blockIdx.x * 1024 + t * 4;
    int v[4]; int s = 0;
    #pragma unroll
    for (int i = 0; i < 4; i++) {
        int idx = base + i;
        v[i] = (idx < N_NODES) ? cnt[idx] : 0;
        s += v[i];
    }
    sd[t] = s; __syncthreads();
    for (int off = 1; off < 256; off <<= 1) {
        int x = (t >= off) ? sd[t - off] : 0;
        __syncthreads();
        sd[t] += x;
        __syncthreads();
    }
    int excl = sd[t] - s + bsum[blockIdx.x];
    #pragma unroll
    for (int i = 0; i < 4; i++) {
        int idx = base + i;
        if (idx < N_NODES) {
            row_ptr[idx] = excl;
            cnt[idx] = excl;                       // becomes `next`
            dinv[idx] = rsqrtf(1.0f + (float)v[i]);
        }
        excl += v[i];
    }
}

// payload store via atomicExch -> memory-side op, no L2 partial-line writeback
__global__ __launch_bounds__(256) void k_fill(const int* __restrict__ rowi,
                                              const int* __restrict__ coli,
                                              int* __restrict__ next,
                                              int* __restrict__ esrc) {
    int e = blockIdx.x * 256 + threadIdx.x;
    if (e < N_EDGES) {
        int p = atomicAdd(&next[coli[e]], 1);
        atomicExch(&esrc[p], rowi[e]);
    }
}

// ============ W1 -> bf16 transposed Wt[col][k] ============

__global__ __launch_bounds__(256) void k_transW(const float* __restrict__ W1,
                                                ushort* __restrict__ Wt) {
    int t = blockIdx.x * 256 + threadIdx.x;   // 32768
    int c = t & 127, k = t >> 7;
    Wt[c * 256 + k] = (ushort)bf16_rn(W1[k * 128 + c]);
}

// ============ GEMM1 (MFMA bf16): g1 = bf16(dinv * (x @ W1)) ============

__global__ __launch_bounds__(256) void k_gemm1(const float* __restrict__ x,
                                               const ushort* __restrict__ Wt,
                                               const float* __restrict__ dinv,
                                               ushort* __restrict__ g1) {
    __shared__ ushort Al[128 * 40];
    __shared__ ushort Bl[128 * 40];
    const int tid = threadIdx.x;
    const int w = tid >> 6;
    const int l = tid & 63;
    const int m = l & 15;
    const int q = l >> 4;
    const int R0 = blockIdx.x * 128;

    const int srow = tid >> 1;
    const int soff = (tid & 1) * 16;

    int vr = R0 + srow; if (vr > N_NODES - 1) vr = N_NODES - 1;
    const float*  xrow = &x[(size_t)vr * F_IN + soff];
    const ushort* wrow = &Wt[srow * 256 + soff];

    float4v acc[2][8];
    #pragma unroll
    for (int i = 0; i < 2; i++)
        #pragma unroll
        for (int j = 0; j < 8; j++) acc[i][j] = (float4v){0.f, 0.f, 0.f, 0.f};

    for (int kt = 0; kt < F_IN; kt += 32) {
        float4 f0 = *(const float4*)&xrow[kt + 0];
        float4 f1 = *(const float4*)&xrow[kt + 4];
        float4 f2 = *(const float4*)&xrow[kt + 8];
        float4 f3 = *(const float4*)&xrow[kt + 12];
        uint4 wv0 = *(const uint4*)&wrow[kt + 0];
        uint4 wv1 = *(const uint4*)&wrow[kt + 8];
        uint4 pa, pb;
        pa.x = pk2(f0.x, f0.y); pa.y = pk2(f0.z, f0.w);
        pa.z = pk2(f1.x, f1.y); pa.w = pk2(f1.z, f1.w);
        pb.x = pk2(f2.x, f2.y); pb.y = pk2(f2.z, f2.w);
        pb.z = pk2(f3.x, f3.y); pb.w = pk2(f3.z, f3.w);
        *(uint4*)&Al[srow * 40 + soff]     = pa;
        *(uint4*)&Al[srow * 40 + soff + 8] = pb;
        *(uint4*)&Bl[srow * 40 + soff]     = wv0;
        *(uint4*)&Bl[srow * 40 + soff + 8] = wv1;
        __syncthreads();

        short8 af0 = *(const short8*)&Al[(w * 32 + m) * 40 + q * 8];
        short8 af1 = *(const short8*)&Al[(w * 32 + 16 + m) * 40 + q * 8];
        #pragma unroll
        for (int n = 0; n < 8; n++) {
            short8 bfr = *(const short8*)&Bl[(n * 16 + m) * 40 + q * 8];
            acc[0][n] = __builtin_amdgcn_mfma_f32_16x16x32_bf16(af0, bfr, acc[0][n], 0, 0, 0);
            acc[1][n] = __builtin_amdgcn_mfma_f32_16x16x32_bf16(af1, bfr, acc[1][n], 0, 0, 0);
        }
        __syncthreads();
    }

    const int rbase = R0 + w * 32 + q * 4;
    float dv0[4], dv1[4];
    #pragma unroll
    for (int r = 0; r < 4; r++) {
        int v0 = rbase + r;      dv0[r] = (v0 < N_NODES) ? dinv[v0] : 0.f;
        int v1 = rbase + 16 + r; dv1[r] = (v1 < N_NODES) ? dinv[v1] : 0.f;
    }
    #pragma unroll
    for (int n = 0; n < 8; n++) {
        #pragma unroll
        for (int r = 0; r < 4; r++) {
            int v0 = rbase + r;
            if (v0 < N_NODES)
                g1[v0 * F_HID + n * 16 + m] = (ushort)bf16_rn(dv0[r] * acc[0][n][r]);
            int v1 = rbase + 16 + r;
            if (v1 < N_NODES)
                g1[v1 * F_HID + n * 16 + m] = (ushort)bf16_rn(dv1[r] * acc[1][n][r]);
        }
    }
}

// ============ aggregate layer 1 (gather, wave/node, bf16 g1, 4-deep MLP) ====

__global__ __launch_bounds__(256) void k_agg1(const int* __restrict__ row_ptr,
                                              const int* __restrict__ esrc,
                                              const float* __restrict__ dinv,
                                              const unsigned int* __restrict__ g1,
                                              const float* __restrict__ b1,
                                              float* __restrict__ h1b) {
    int node = blockIdx.x * 4 + (threadIdx.x >> 6);
    int lane = threadIdx.x & 63;
    if (node >= N_NODES) return;
    int s = row_ptr[node], t = row_ptr[node + 1];
    unsigned int u = g1[node * 64 + lane];     // self-loop
    float ax = __uint_as_float(u << 16);
    float ay = __uint_as_float(u & 0xFFFF0000u);
    int e = s;
    for (; e + 3 < t; e += 4) {
        int r0 = esrc[e], r1 = esrc[e + 1], r2 = esrc[e + 2], r3 = esrc[e + 3];
        unsigned int u0 = g1[r0 * 64 + lane];
        unsigned int u1 = g1[r1 * 64 + lane];
        unsigned int u2 = g1[r2 * 64 + lane];
        unsigned int u3 = g1[r3 * 64 + lane];
        ax += __uint_as_float(u0 << 16) + __uint_as_float(u1 << 16)
            + __uint_as_float(u2 << 16) + __uint_as_float(u3 << 16);
        ay += __uint_as_float(u0 & 0xFFFF0000u) + __uint_as_float(u1 & 0xFFFF0000u)
            + __uint_as_float(u2 & 0xFFFF0000u) + __uint_as_float(u3 & 0xFFFF0000u);
    }
    for (; e < t; e++) {
        unsigned int u0 = g1[esrc[e] * 64 + lane];
        ax += __uint_as_float(u0 << 16);
        ay += __uint_as_float(u0 & 0xFFFF0000u);
    }
    float wv = dinv[node];
    float2 bb = ((const float2*)b1)[lane];
    float2 o;
    o.x = fmaxf(fmaf(wv, ax, bb.x), 0.0f);
    o.y = fmaxf(fmaf(wv, ay, bb.y), 0.0f);
    ((float2*)h1b)[node * 64 + lane] = o;
}

// ============ GEMM2: g2 = dinv * (h1b @ W2) ============

__global__ __launch_bounds__(256) void k_gemm2(const float* __restrict__ h1b,
                                               const float* __restrict__ W2,
                                               const float* __restrict__ dinv,
                                               float* __restrict__ g2) {
    __shared__ float ls[64 * 129];
    __shared__ float ws2[F_HID * F_OUT];
    const int tid = threadIdx.x;
    const int v0  = blockIdx.x * 64;

    for (int i = tid; i < F_HID * F_OUT; i += 256) ws2[i] = W2[i];
    __syncthreads();

    #pragma unroll
    for (int i = 0; i < 32; i++) {
        int f = i * 256 + tid;
        int rr = f >> 7, cc = f & 127;
        int v = v0 + rr;
        ls[rr * 129 + cc] = (v < N_NODES) ? h1b[v * F_HID + cc] : 0.0f;
    }
    __syncthreads();

    const int v  = tid >> 2;
    const int cq = (tid & 3) * 4;
    float acc[4] = {0.f, 0.f, 0.f, 0.f};
    #pragma unroll 8
    for (int f = 0; f < F_HID; f++) {
        float a = ls[v * 129 + f];
        #pragma unroll
        for (int j = 0; j < 4; j++)
            acc[j] = fmaf(a, ws2[f * F_OUT + cq + j], acc[j]);
    }
    int vv = v0 + v;
    if (vv < N_NODES) {
        float w = dinv[vv];
        float4 t = make_float4(w * acc[0], w * acc[1], w * acc[2], w * acc[3]);
        *(float4*)&g2[vv * F_OUT + cq] = t;
    }
}

// ============ aggregate layer 2 ============

__global__ __launch_bounds__(256) void k_agg2(const int* __restrict__ row_ptr,
                                              const int* __restrict__ esrc,
                                              const float* __restrict__ dinv,
                                              const float* __restrict__ g2,
                                              const float* __restrict__ b2,
                                              float* __restrict__ out) {
    int gid = blockIdx.x * 256 + threadIdx.x;
    int node = gid >> 4;
    int f = gid & 15;
    if (node >= N_NODES) return;
    int s = row_ptr[node], t = row_ptr[node + 1];
    float acc = g2[node * 16 + f];
    int e = s;
    for (; e + 3 < t; e += 4) {
        acc += g2[esrc[e] * 16 + f] + g2[esrc[e + 1] * 16 + f]
             + g2[esrc[e + 2] * 16 + f] + g2[esrc[e + 3] * 16 + f];
    }
    for (; e < t; e++) acc += g2[esrc[e] * 16 + f];
    out[node * 16 + f] = fmaf(dinv[node], acc, b2[f]);
}

// ======================= launch =======================

extern "C" void kernel_launch(void* const* d_in, const int* in_sizes, int n_in,
                              void* d_out, int out_size, void* d_ws, size_t ws_size,
                              hipStream_t stream) {
    const float* x   = (const float*)d_in[0];
    const int*   ei  = (const int*)d_in[1];
    const float* W1  = (const float*)d_in[2];
    const float* b1  = (const float*)d_in[3];
    const float* W2  = (const float*)d_in[4];
    const float* b2  = (const float*)d_in[5];
    float* out = (float*)d_out;

    const int* rowi = ei;
    const int* coli = ei + N_EDGES;

    char* ws = (char*)d_ws;
    int*    cnt     = (int*)(ws + 0);            // 400KB, reused as `next`
    int*    row_ptr = (int*)(ws + 524288);
    float*  dinv    = (float*)(ws + 1048576);
    int*    bsum    = (int*)(ws + 1572864);
    int*    esrc    = (int*)(ws + 2097152);      // 6.4 MB
    ushort* Wt      = (ushort*)(ws + 8519680);   // 64 KB bf16 W1^T
    ushort* g1      = (ushort*)(ws + 8650752);   // 25.6 MB bf16
    float*  g2      = (float*)(ws + 8650752);    // reuses g1 (dead after agg1)
    float*  h1b     = (float*)(ws + 34603008);   // 51.2 MB

    hipMemsetAsync(cnt, 0, N_NODES * sizeof(int), stream);

    k_hist        <<<(N_EDGES + 255) / 256, 256, 0, stream>>>(coli, cnt);
    k_scan_partial<<<SCAN_BLOCKS, 256, 0, stream>>>(cnt, bsum);
    k_scan_top    <<<1, 128, 0, stream>>>(bsum, row_ptr);
    k_scan_final  <<<SCAN_BLOCKS, 256, 0, stream>>>(cnt, bsum, row_ptr, dinv);
    k_fill        <<<(N_EDGES + 255) / 256, 256, 0, stream>>>(rowi, coli, cnt, esrc);
    k_transW      <<<128, 256, 0, stream>>>(W1, Wt);

    k_gemm1       <<<(N_NODES + 127) / 128, 256, 0, stream>>>(x, Wt, dinv, g1);
    k_agg1        <<<(N_NODES + 3) / 4, 256, 0, stream>>>(row_ptr, esrc, dinv,
                                                          (const unsigned int*)g1, b1, h1b);
    k_gemm2       <<<(N_NODES + 63) / 64, 256, 0, stream>>>(h1b, W2, dinv, g2);
    k_agg2        <<<(N_NODES * 16 + 255) / 256, 256, 0, stream>>>(row_ptr, esrc, dinv, g2, b2, out);
}

// Round 5
// 396.755 us; speedup vs baseline: 8.5684x; 1.3736x over previous
//
#include <hip/hip_runtime.h>

#define N_NODES 100000
#define N_EDGES 1600000
#define F_IN    256
#define F_HID   128
#define F_OUT   16

#define BSHIFT  9
#define BNODES  512                 // nodes per bucket
#define NB      196                 // ceil(100000/512)
#define CHUNK   4096
#define NCHUNK  ((N_EDGES + CHUNK - 1) / CHUNK)   // 391

typedef __attribute__((ext_vector_type(8))) short short8;
typedef __attribute__((ext_vector_type(4))) float float4v;

__device__ __forceinline__ unsigned int bf16_rn(float f) {
    unsigned int u = __float_as_uint(f);
    return (u + 0x7FFFu + ((u >> 16) & 1u)) >> 16;
}
__device__ __forceinline__ unsigned int pk2(float lo, float hi) {
    return bf16_rn(lo) | (bf16_rn(hi) << 16);
}

// ======================= bucketed CSR build =======================

__global__ __launch_bounds__(256) void k_bhist(const int* __restrict__ coli,
                                               int* __restrict__ bcnt) {
    __shared__ int lc[NB];
    int tid = threadIdx.x;
    for (int i = tid; i < NB; i += 256) lc[i] = 0;
    __syncthreads();
    for (int e = blockIdx.x * 256 + tid; e < N_EDGES; e += 256 * 256)
        atomicAdd(&lc[coli[e] >> BSHIFT], 1);
    __syncthreads();
    for (int i = tid; i < NB; i += 256)
        if (lc[i]) atomicAdd(&bcnt[i], lc[i]);
}

__global__ __launch_bounds__(256) void k_bscan(const int* __restrict__ bcnt,
                                               int* __restrict__ bbase,
                                               int* __restrict__ bcur) {
    __shared__ int sc[256];
    int t = threadIdx.x;
    int v = (t < NB) ? bcnt[t] : 0;
    sc[t] = v; __syncthreads();
    for (int off = 1; off < 256; off <<= 1) {
        int x = (t >= off) ? sc[t - off] : 0;
        __syncthreads();
        sc[t] += x;
        __syncthreads();
    }
    if (t < NB) {
        int e = sc[t] - v;         // exclusive
        bbase[t] = e;
        bcur[t]  = e;
    }
    if (t == 0) bbase[NB] = N_EDGES;
}

// per-block LDS count -> one global reservation per bucket -> grouped writes
__global__ __launch_bounds__(256) void k_binscatter(const int* __restrict__ rowi,
                                                    const int* __restrict__ coli,
                                                    int* __restrict__ bcur,
                                                    int2* __restrict__ ebuf) {
    __shared__ int cnt[NB], gbase[NB], run[NB];
    int tid = threadIdx.x;
    int e0 = blockIdx.x * CHUNK;
    for (int i = tid; i < NB; i += 256) { cnt[i] = 0; run[i] = 0; }
    __syncthreads();
    int d[16], s[16];
    #pragma unroll
    for (int i = 0; i < 16; i++) {
        int e = e0 + i * 256 + tid;
        if (e < N_EDGES) {
            d[i] = coli[e]; s[i] = rowi[e];
            atomicAdd(&cnt[d[i] >> BSHIFT], 1);
        } else d[i] = -1;
    }
    __syncthreads();
    for (int i = tid; i < NB; i += 256)
        gbase[i] = cnt[i] ? atomicAdd(&bcur[i], cnt[i]) : 0;
    __syncthreads();
    #pragma unroll
    for (int i = 0; i < 16; i++) {
        if (d[i] >= 0) {
            int b = d[i] >> BSHIFT;
            int off = atomicAdd(&run[b], 1);
            ebuf[gbase[b] + off] = make_int2(d[i], s[i]);
        }
    }
}

// one workgroup per bucket: per-node degree, scan, row_ptr/dinv, local esrc fill
__global__ __launch_bounds__(256) void k_finalize(const int* __restrict__ bbase,
                                                  const int2* __restrict__ ebuf,
                                                  int* __restrict__ row_ptr,
                                                  float* __restrict__ dinv,
                                                  int* __restrict__ esrc) {
    __shared__ int ndeg[BNODES];
    __shared__ int sc[BNODES];
    int tid = threadIdx.x;
    int b   = blockIdx.x;
    int nb0 = b << BSHIFT;
    int ebeg = bbase[b], eend = bbase[b + 1];
    ndeg[tid] = 0; ndeg[tid + 256] = 0;
    __syncthreads();
    for (int e = ebeg + tid; e < eend; e += 256)
        atomicAdd(&ndeg[ebuf[e].x - nb0], 1);
    __syncthreads();
    // inclusive scan over 512
    int i0 = tid, i1 = tid + 256;
    sc[i0] = ndeg[i0]; sc[i1] = ndeg[i1];
    __syncthreads();
    for (int off = 1; off < BNODES; off <<= 1) {
        int v0 = (i0 >= off) ? sc[i0 - off] : 0;
        int v1 = (i1 >= off) ? sc[i1 - off] : 0;
        __syncthreads();
        sc[i0] += v0; sc[i1] += v1;
        __syncthreads();
    }
    #pragma unroll
    for (int k = 0; k < 2; k++) {
        int i = tid + k * 256;
        int n = nb0 + i;
        int deg = ndeg[i];
        int excl = sc[i] - deg;
        if (n < N_NODES) {
            row_ptr[n] = ebeg + excl;
            dinv[n]    = rsqrtf(1.0f + (float)deg);
        }
        ndeg[i] = excl;                // becomes local cursor
    }
    if (b == NB - 1 && tid == 0) row_ptr[N_NODES] = N_EDGES;
    __syncthreads();
    for (int e = ebeg + tid; e < eend; e += 256) {
        int2 p = ebuf[e];
        int off = atomicAdd(&ndeg[p.x - nb0], 1);
        esrc[ebeg + off] = p.y;        // confined to this bucket's window
    }
}

// ============ W1 -> bf16 transposed Wt[col][k] ============

__global__ __launch_bounds__(256) void k_transW(const float* __restrict__ W1,
                                                ushort* __restrict__ Wt) {
    int t = blockIdx.x * 256 + threadIdx.x;   // 32768
    int c = t & 127, k = t >> 7;
    Wt[c * 256 + k] = (ushort)bf16_rn(W1[k * 128 + c]);
}

// ============ GEMM1 (MFMA bf16): g1 = bf16(dinv * (x @ W1)) ============

__global__ __launch_bounds__(256) void k_gemm1(const float* __restrict__ x,
                                               const ushort* __restrict__ Wt,
                                               const float* __restrict__ dinv,
                                               ushort* __restrict__ g1) {
    __shared__ ushort Al[128 * 40];
    __shared__ ushort Bl[128 * 40];
    const int tid = threadIdx.x;
    const int w = tid >> 6;
    const int l = tid & 63;
    const int m = l & 15;
    const int q = l >> 4;
    const int R0 = blockIdx.x * 128;

    const int srow = tid >> 1;
    const int soff = (tid & 1) * 16;

    int vr = R0 + srow; if (vr > N_NODES - 1) vr = N_NODES - 1;
    const float*  xrow = &x[(size_t)vr * F_IN + soff];
    const ushort* wrow = &Wt[srow * 256 + soff];

    float4v acc[2][8];
    #pragma unroll
    for (int i = 0; i < 2; i++)
        #pragma unroll
        for (int j = 0; j < 8; j++) acc[i][j] = (float4v){0.f, 0.f, 0.f, 0.f};

    for (int kt = 0; kt < F_IN; kt += 32) {
        float4 f0 = *(const float4*)&xrow[kt + 0];
        float4 f1 = *(const float4*)&xrow[kt + 4];
        float4 f2 = *(const float4*)&xrow[kt + 8];
        float4 f3 = *(const float4*)&xrow[kt + 12];
        uint4 wv0 = *(const uint4*)&wrow[kt + 0];
        uint4 wv1 = *(const uint4*)&wrow[kt + 8];
        uint4 pa, pb;
        pa.x = pk2(f0.x, f0.y); pa.y = pk2(f0.z, f0.w);
        pa.z = pk2(f1.x, f1.y); pa.w = pk2(f1.z, f1.w);
        pb.x = pk2(f2.x, f2.y); pb.y = pk2(f2.z, f2.w);
        pb.z = pk2(f3.x, f3.y); pb.w = pk2(f3.z, f3.w);
        *(uint4*)&Al[srow * 40 + soff]     = pa;
        *(uint4*)&Al[srow * 40 + soff + 8] = pb;
        *(uint4*)&Bl[srow * 40 + soff]     = wv0;
        *(uint4*)&Bl[srow * 40 + soff + 8] = wv1;
        __syncthreads();

        short8 af0 = *(const short8*)&Al[(w * 32 + m) * 40 + q * 8];
        short8 af1 = *(const short8*)&Al[(w * 32 + 16 + m) * 40 + q * 8];
        #pragma unroll
        for (int n = 0; n < 8; n++) {
            short8 bfr = *(const short8*)&Bl[(n * 16 + m) * 40 + q * 8];
            acc[0][n] = __builtin_amdgcn_mfma_f32_16x16x32_bf16(af0, bfr, acc[0][n], 0, 0, 0);
            acc[1][n] = __builtin_amdgcn_mfma_f32_16x16x32_bf16(af1, bfr, acc[1][n], 0, 0, 0);
        }
        __syncthreads();
    }

    const int rbase = R0 + w * 32 + q * 4;
    float dv0[4], dv1[4];
    #pragma unroll
    for (int r = 0; r < 4; r++) {
        int v0 = rbase + r;      dv0[r] = (v0 < N_NODES) ? dinv[v0] : 0.f;
        int v1 = rbase + 16 + r; dv1[r] = (v1 < N_NODES) ? dinv[v1] : 0.f;
    }
    #pragma unroll
    for (int n = 0; n < 8; n++) {
        #pragma unroll
        for (int r = 0; r < 4; r++) {
            int v0 = rbase + r;
            if (v0 < N_NODES)
                g1[v0 * F_HID + n * 16 + m] = (ushort)bf16_rn(dv0[r] * acc[0][n][r]);
            int v1 = rbase + 16 + r;
            if (v1 < N_NODES)
                g1[v1 * F_HID + n * 16 + m] = (ushort)bf16_rn(dv1[r] * acc[1][n][r]);
        }
    }
}

// ============ aggregate layer 1 (gather, wave/node, bf16 g1, 4-deep MLP) ====

__global__ __launch_bounds__(256) void k_agg1(const int* __restrict__ row_ptr,
                                              const int* __restrict__ esrc,
                                              const float* __restrict__ dinv,
                                              const unsigned int* __restrict__ g1,
                                              const float* __restrict__ b1,
                                              float* __restrict__ h1b) {
    int node = blockIdx.x * 4 + (threadIdx.x >> 6);
    int lane = threadIdx.x & 63;
    if (node >= N_NODES) return;
    int s = row_ptr[node], t = row_ptr[node + 1];
    unsigned int u = g1[node * 64 + lane];     // self-loop
    float ax = __uint_as_float(u << 16);
    float ay = __uint_as_float(u & 0xFFFF0000u);
    int e = s;
    for (; e + 3 < t; e += 4) {
        int r0 = esrc[e], r1 = esrc[e + 1], r2 = esrc[e + 2], r3 = esrc[e + 3];
        unsigned int u0 = g1[r0 * 64 + lane];
        unsigned int u1 = g1[r1 * 64 + lane];
        unsigned int u2 = g1[r2 * 64 + lane];
        unsigned int u3 = g1[r3 * 64 + lane];
        ax += __uint_as_float(u0 << 16) + __uint_as_float(u1 << 16)
            + __uint_as_float(u2 << 16) + __uint_as_float(u3 << 16);
        ay += __uint_as_float(u0 & 0xFFFF0000u) + __uint_as_float(u1 & 0xFFFF0000u)
            + __uint_as_float(u2 & 0xFFFF0000u) + __uint_as_float(u3 & 0xFFFF0000u);
    }
    for (; e < t; e++) {
        unsigned int u0 = g1[esrc[e] * 64 + lane];
        ax += __uint_as_float(u0 << 16);
        ay += __uint_as_float(u0 & 0xFFFF0000u);
    }
    float wv = dinv[node];
    float2 bb = ((const float2*)b1)[lane];
    float2 o;
    o.x = fmaxf(fmaf(wv, ax, bb.x), 0.0f);
    o.y = fmaxf(fmaf(wv, ay, bb.y), 0.0f);
    ((float2*)h1b)[node * 64 + lane] = o;
}

// ============ GEMM2: g2 = dinv * (h1b @ W2) ============

__global__ __launch_bounds__(256) void k_gemm2(const float* __restrict__ h1b,
                                               const float* __restrict__ W2,
                                               const float* __restrict__ dinv,
                                               float* __restrict__ g2) {
    __shared__ float ls[64 * 129];
    __shared__ float ws2[F_HID * F_OUT];
    const int tid = threadIdx.x;
    const int v0  = blockIdx.x * 64;

    for (int i = tid; i < F_HID * F_OUT; i += 256) ws2[i] = W2[i];
    __syncthreads();

    #pragma unroll
    for (int i = 0; i < 32; i++) {
        int f = i * 256 + tid;
        int rr = f >> 7, cc = f & 127;
        int v = v0 + rr;
        ls[rr * 129 + cc] = (v < N_NODES) ? h1b[v * F_HID + cc] : 0.0f;
    }
    __syncthreads();

    const int v  = tid >> 2;
    const int cq = (tid & 3) * 4;
    float acc[4] = {0.f, 0.f, 0.f, 0.f};
    #pragma unroll 8
    for (int f = 0; f < F_HID; f++) {
        float a = ls[v * 129 + f];
        #pragma unroll
        for (int j = 0; j < 4; j++)
            acc[j] = fmaf(a, ws2[f * F_OUT + cq + j], acc[j]);
    }
    int vv = v0 + v;
    if (vv < N_NODES) {
        float w = dinv[vv];
        float4 t = make_float4(w * acc[0], w * acc[1], w * acc[2], w * acc[3]);
        *(float4*)&g2[vv * F_OUT + cq] = t;
    }
}

// ============ aggregate layer 2 ============

__global__ __launch_bounds__(256) void k_agg2(const int* __restrict__ row_ptr,
                                              const int* __restrict__ esrc,
                                              const float* __restrict__ dinv,
                                              const float* __restrict__ g2,
                                              const float* __restrict__ b2,
                                              float* __restrict__ out) {
    int gid = blockIdx.x * 256 + threadIdx.x;
    int node = gid >> 4;
    int f = gid & 15;
    if (node >= N_NODES) return;
    int s = row_ptr[node], t = row_ptr[node + 1];
    float acc = g2[node * 16 + f];
    int e = s;
    for (; e + 3 < t; e += 4) {
        acc += g2[esrc[e] * 16 + f] + g2[esrc[e + 1] * 16 + f]
             + g2[esrc[e + 2] * 16 + f] + g2[esrc[e + 3] * 16 + f];
    }
    for (; e < t; e++) acc += g2[esrc[e] * 16 + f];
    out[node * 16 + f] = fmaf(dinv[node], acc, b2[f]);
}

// ======================= launch =======================

extern "C" void kernel_launch(void* const* d_in, const int* in_sizes, int n_in,
                              void* d_out, int out_size, void* d_ws, size_t ws_size,
                              hipStream_t stream) {
    const float* x   = (const float*)d_in[0];
    const int*   ei  = (const int*)d_in[1];
    const float* W1  = (const float*)d_in[2];
    const float* b1  = (const float*)d_in[3];
    const float* W2  = (const float*)d_in[4];
    const float* b2  = (const float*)d_in[5];
    float* out = (float*)d_out;

    const int* rowi = ei;             // sources
    const int* coli = ei + N_EDGES;   // targets

    char* ws = (char*)d_ws;
    int*    bcnt    = (int*)(ws + 0);
    int*    bbase   = (int*)(ws + 4096);
    int*    bcur    = (int*)(ws + 8192);
    int*    row_ptr = (int*)(ws + 16384);        // 400 KB + 4
    float*  dinv    = (float*)(ws + 524288);     // 400 KB
    int2*   ebuf    = (int2*)(ws + 1048576);     // 12.8 MB
    int*    esrc    = (int*)(ws + 14680064);     // 6.4 MB
    ushort* Wt      = (ushort*)(ws + 22020096);  // 64 KB
    ushort* g1      = (ushort*)(ws + 23068672);  // 25.6 MB bf16
    float*  g2      = (float*)(ws + 23068672);   // reuses g1 (dead after agg1)
    float*  h1b     = (float*)(ws + 50331648);   // 51.2 MB

    hipMemsetAsync(bcnt, 0, NB * sizeof(int), stream);

    k_bhist     <<<256, 256, 0, stream>>>(coli, bcnt);
    k_bscan     <<<1, 256, 0, stream>>>(bcnt, bbase, bcur);
    k_binscatter<<<NCHUNK, 256, 0, stream>>>(rowi, coli, bcur, ebuf);
    k_finalize  <<<NB, 256, 0, stream>>>(bbase, ebuf, row_ptr, dinv, esrc);
    k_transW    <<<128, 256, 0, stream>>>(W1, Wt);

    k_gemm1     <<<(N_NODES + 127) / 128, 256, 0, stream>>>(x, Wt, dinv, g1);
    k_agg1      <<<(N_NODES + 3) / 4, 256, 0, stream>>>(row_ptr, esrc, dinv,
                                                        (const unsigned int*)g1, b1, h1b);
    k_gemm2     <<<(N_NODES + 63) / 64, 256, 0, stream>>>(h1b, W2, dinv, g2);
    k_agg2      <<<(N_NODES * 16 + 255) / 256, 256, 0, stream>>>(row_ptr, esrc, dinv, g2, b2, out);
}

// Round 6
// 371.501 us; speedup vs baseline: 9.1509x; 1.0680x over previous
//
#include <hip/hip_runtime.h>

#define N_NODES 100000
#define N_EDGES 1600000
#define F_IN    256
#define F_HID   128
#define F_OUT   16

#define BSHIFT  9
#define BNODES  512
#define NB      196                 // ceil(100000/512)
#define CHUNK   4096
#define NCHUNK  ((N_EDGES + CHUNK - 1) / CHUNK)   // 391

typedef __attribute__((ext_vector_type(8))) short short8;
typedef __attribute__((ext_vector_type(4))) float float4v;

__device__ __forceinline__ unsigned int bf16_rn(float f) {
    unsigned int u = __float_as_uint(f);
    return (u + 0x7FFFu + ((u >> 16) & 1u)) >> 16;
}
__device__ __forceinline__ unsigned int pk2(float lo, float hi) {
    return bf16_rn(lo) | (bf16_rn(hi) << 16);
}
__device__ __forceinline__ float blo(unsigned int u) { return __uint_as_float(u << 16); }
__device__ __forceinline__ float bhi(unsigned int u) { return __uint_as_float(u & 0xFFFF0000u); }

// ======================= bucketed CSR build =======================

__global__ __launch_bounds__(256) void k_bhist(const int* __restrict__ coli,
                                               int* __restrict__ bcnt) {
    __shared__ int lc[NB];
    int tid = threadIdx.x;
    for (int i = tid; i < NB; i += 256) lc[i] = 0;
    __syncthreads();
    for (int e = blockIdx.x * 256 + tid; e < N_EDGES; e += 256 * 256)
        atomicAdd(&lc[coli[e] >> BSHIFT], 1);
    __syncthreads();
    for (int i = tid; i < NB; i += 256)
        if (lc[i]) atomicAdd(&bcnt[i], lc[i]);
}

__global__ __launch_bounds__(256) void k_bscan(const int* __restrict__ bcnt,
                                               int* __restrict__ bbase,
                                               int* __restrict__ bcur) {
    __shared__ int sc[256];
    int t = threadIdx.x;
    int v = (t < NB) ? bcnt[t] : 0;
    sc[t] = v; __syncthreads();
    for (int off = 1; off < 256; off <<= 1) {
        int x = (t >= off) ? sc[t - off] : 0;
        __syncthreads();
        sc[t] += x;
        __syncthreads();
    }
    if (t < NB) {
        int e = sc[t] - v;
        bbase[t] = e;
        bcur[t]  = e;
    }
    if (t == 0) bbase[NB] = N_EDGES;
}

// per-block LDS count -> one global reservation per bucket -> grouped packed writes
__global__ __launch_bounds__(256) void k_binscatter(const int* __restrict__ rowi,
                                                    const int* __restrict__ coli,
                                                    int* __restrict__ bcur,
                                                    unsigned int* __restrict__ ebuf) {
    __shared__ int cnt[NB], gbase[NB], run[NB];
    int tid = threadIdx.x;
    int e0 = blockIdx.x * CHUNK;
    for (int i = tid; i < NB; i += 256) { cnt[i] = 0; run[i] = 0; }
    __syncthreads();
    int d[16], s[16];
    #pragma unroll
    for (int i = 0; i < 16; i++) {
        int e = e0 + i * 256 + tid;
        if (e < N_EDGES) {
            d[i] = coli[e]; s[i] = rowi[e];
            atomicAdd(&cnt[d[i] >> BSHIFT], 1);
        } else d[i] = -1;
    }
    __syncthreads();
    for (int i = tid; i < NB; i += 256)
        gbase[i] = cnt[i] ? atomicAdd(&bcur[i], cnt[i]) : 0;
    __syncthreads();
    #pragma unroll
    for (int i = 0; i < 16; i++) {
        if (d[i] >= 0) {
            int b = d[i] >> BSHIFT;
            int off = atomicAdd(&run[b], 1);
            ebuf[gbase[b] + off] = ((unsigned int)(d[i] & 511) << 17) | (unsigned int)s[i];
        }
    }
}

// one workgroup per bucket: per-node degree, scan, row_ptr/dinv, local esrc fill
__global__ __launch_bounds__(256) void k_finalize(const int* __restrict__ bbase,
                                                  const unsigned int* __restrict__ ebuf,
                                                  int* __restrict__ row_ptr,
                                                  float* __restrict__ dinv,
                                                  int* __restrict__ esrc) {
    __shared__ int ndeg[BNODES];
    __shared__ int sc[BNODES];
    int tid = threadIdx.x;
    int b   = blockIdx.x;
    int nb0 = b << BSHIFT;
    int ebeg = bbase[b], eend = bbase[b + 1];
    ndeg[tid] = 0; ndeg[tid + 256] = 0;
    __syncthreads();
    for (int e = ebeg + tid; e < eend; e += 256)
        atomicAdd(&ndeg[ebuf[e] >> 17], 1);
    __syncthreads();
    int i0 = tid, i1 = tid + 256;
    sc[i0] = ndeg[i0]; sc[i1] = ndeg[i1];
    __syncthreads();
    for (int off = 1; off < BNODES; off <<= 1) {
        int v0 = (i0 >= off) ? sc[i0 - off] : 0;
        int v1 = (i1 >= off) ? sc[i1 - off] : 0;
        __syncthreads();
        sc[i0] += v0; sc[i1] += v1;
        __syncthreads();
    }
    #pragma unroll
    for (int k = 0; k < 2; k++) {
        int i = tid + k * 256;
        int n = nb0 + i;
        int deg = ndeg[i];
        int excl = sc[i] - deg;
        if (n < N_NODES) {
            row_ptr[n] = ebeg + excl;
            dinv[n]    = rsqrtf(1.0f + (float)deg);
        }
        ndeg[i] = excl;
    }
    if (b == NB - 1 && tid == 0) row_ptr[N_NODES] = N_EDGES;
    __syncthreads();
    for (int e = ebeg + tid; e < eend; e += 256) {
        unsigned int p = ebuf[e];
        int off = atomicAdd(&ndeg[p >> 17], 1);
        esrc[ebeg + off] = (int)(p & 0x1FFFFu);
    }
}

// ============ W1 -> bf16 transposed Wt[col][k] ============

__global__ __launch_bounds__(256) void k_transW(const float* __restrict__ W1,
                                                ushort* __restrict__ Wt) {
    int t = blockIdx.x * 256 + threadIdx.x;
    int c = t & 127, k = t >> 7;
    Wt[c * 256 + k] = (ushort)bf16_rn(W1[k * 128 + c]);
}

// ============ GEMM1 (MFMA bf16): g1 = bf16(dinv * (x @ W1)) ============

__global__ __launch_bounds__(256) void k_gemm1(const float* __restrict__ x,
                                               const ushort* __restrict__ Wt,
                                               const float* __restrict__ dinv,
                                               ushort* __restrict__ g1) {
    __shared__ ushort Al[128 * 40];
    __shared__ ushort Bl[128 * 40];
    const int tid = threadIdx.x;
    const int w = tid >> 6;
    const int l = tid & 63;
    const int m = l & 15;
    const int q = l >> 4;
    const int R0 = blockIdx.x * 128;

    const int srow = tid >> 1;
    const int soff = (tid & 1) * 16;

    int vr = R0 + srow; if (vr > N_NODES - 1) vr = N_NODES - 1;
    const float*  xrow = &x[(size_t)vr * F_IN + soff];
    const ushort* wrow = &Wt[srow * 256 + soff];

    float4v acc[2][8];
    #pragma unroll
    for (int i = 0; i < 2; i++)
        #pragma unroll
        for (int j = 0; j < 8; j++) acc[i][j] = (float4v){0.f, 0.f, 0.f, 0.f};

    for (int kt = 0; kt < F_IN; kt += 32) {
        float4 f0 = *(const float4*)&xrow[kt + 0];
        float4 f1 = *(const float4*)&xrow[kt + 4];
        float4 f2 = *(const float4*)&xrow[kt + 8];
        float4 f3 = *(const float4*)&xrow[kt + 12];
        uint4 wv0 = *(const uint4*)&wrow[kt + 0];
        uint4 wv1 = *(const uint4*)&wrow[kt + 8];
        uint4 pa, pb;
        pa.x = pk2(f0.x, f0.y); pa.y = pk2(f0.z, f0.w);
        pa.z = pk2(f1.x, f1.y); pa.w = pk2(f1.z, f1.w);
        pb.x = pk2(f2.x, f2.y); pb.y = pk2(f2.z, f2.w);
        pb.z = pk2(f3.x, f3.y); pb.w = pk2(f3.z, f3.w);
        *(uint4*)&Al[srow * 40 + soff]     = pa;
        *(uint4*)&Al[srow * 40 + soff + 8] = pb;
        *(uint4*)&Bl[srow * 40 + soff]     = wv0;
        *(uint4*)&Bl[srow * 40 + soff + 8] = wv1;
        __syncthreads();

        short8 af0 = *(const short8*)&Al[(w * 32 + m) * 40 + q * 8];
        short8 af1 = *(const short8*)&Al[(w * 32 + 16 + m) * 40 + q * 8];
        #pragma unroll
        for (int n = 0; n < 8; n++) {
            short8 bfr = *(const short8*)&Bl[(n * 16 + m) * 40 + q * 8];
            acc[0][n] = __builtin_amdgcn_mfma_f32_16x16x32_bf16(af0, bfr, acc[0][n], 0, 0, 0);
            acc[1][n] = __builtin_amdgcn_mfma_f32_16x16x32_bf16(af1, bfr, acc[1][n], 0, 0, 0);
        }
        __syncthreads();
    }

    const int rbase = R0 + w * 32 + q * 4;
    float dv0[4], dv1[4];
    #pragma unroll
    for (int r = 0; r < 4; r++) {
        int v0 = rbase + r;      dv0[r] = (v0 < N_NODES) ? dinv[v0] : 0.f;
        int v1 = rbase + 16 + r; dv1[r] = (v1 < N_NODES) ? dinv[v1] : 0.f;
    }
    #pragma unroll
    for (int n = 0; n < 8; n++) {
        #pragma unroll
        for (int r = 0; r < 4; r++) {
            int v0 = rbase + r;
            if (v0 < N_NODES)
                g1[v0 * F_HID + n * 16 + m] = (ushort)bf16_rn(dv0[r] * acc[0][n][r]);
            int v1 = rbase + 16 + r;
            if (v1 < N_NODES)
                g1[v1 * F_HID + n * 16 + m] = (ushort)bf16_rn(dv1[r] * acc[1][n][r]);
        }
    }
}

// ==== fused agg1 + GEMM2: g2 = dinv * (relu(dinv*(sum g1) + b1) @ W2) ====
// 4 waves/block = 4 nodes; 8-deep gather; h1b row via LDS; part-split dot.

__global__ __launch_bounds__(256) void k_agg1g2(const int* __restrict__ row_ptr,
                                                const int* __restrict__ esrc,
                                                const float* __restrict__ dinv,
                                                const unsigned int* __restrict__ g1,
                                                const float* __restrict__ b1,
                                                const float* __restrict__ W2,
                                                float* __restrict__ g2) {
    __shared__ float hl[4 * 132];
    __shared__ float W2s[F_HID * F_OUT];
    const int tid  = threadIdx.x;
    const int wave = tid >> 6;
    const int lane = tid & 63;
    const int node = blockIdx.x * 4 + wave;   // 25000*4 == N_NODES exactly

    for (int i = tid; i < F_HID * F_OUT; i += 256) W2s[i] = W2[i];

    int s = row_ptr[node], t = row_ptr[node + 1];
    unsigned int u = g1[node * 64 + lane];     // self-loop
    float ax = blo(u), ay = bhi(u);
    int e = s;
    for (; e + 7 < t; e += 8) {
        int r0 = esrc[e],     r1 = esrc[e + 1], r2 = esrc[e + 2], r3 = esrc[e + 3];
        int r4 = esrc[e + 4], r5 = esrc[e + 5], r6 = esrc[e + 6], r7 = esrc[e + 7];
        unsigned int u0 = g1[r0 * 64 + lane], u1 = g1[r1 * 64 + lane];
        unsigned int u2 = g1[r2 * 64 + lane], u3 = g1[r3 * 64 + lane];
        unsigned int u4 = g1[r4 * 64 + lane], u5 = g1[r5 * 64 + lane];
        unsigned int u6 = g1[r6 * 64 + lane], u7 = g1[r7 * 64 + lane];
        ax += blo(u0) + blo(u1) + blo(u2) + blo(u3)
            + blo(u4) + blo(u5) + blo(u6) + blo(u7);
        ay += bhi(u0) + bhi(u1) + bhi(u2) + bhi(u3)
            + bhi(u4) + bhi(u5) + bhi(u6) + bhi(u7);
    }
    for (; e + 3 < t; e += 4) {
        int r0 = esrc[e], r1 = esrc[e + 1], r2 = esrc[e + 2], r3 = esrc[e + 3];
        unsigned int u0 = g1[r0 * 64 + lane], u1 = g1[r1 * 64 + lane];
        unsigned int u2 = g1[r2 * 64 + lane], u3 = g1[r3 * 64 + lane];
        ax += blo(u0) + blo(u1) + blo(u2) + blo(u3);
        ay += bhi(u0) + bhi(u1) + bhi(u2) + bhi(u3);
    }
    for (; e < t; e++) {
        unsigned int u0 = g1[esrc[e] * 64 + lane];
        ax += blo(u0); ay += bhi(u0);
    }
    float wv = dinv[node];
    float2 bb = ((const float2*)b1)[lane];
    hl[wave * 132 + lane * 2]     = fmaxf(fmaf(wv, ax, bb.x), 0.0f);
    hl[wave * 132 + lane * 2 + 1] = fmaxf(fmaf(wv, ay, bb.y), 0.0f);
    __syncthreads();

    // epilogue: 16 cols x 4 parts per wave; f = i*4 + part (bank-friendly)
    const int col = lane & 15, part = lane >> 4;
    float acc = 0.f;
    #pragma unroll
    for (int i = 0; i < 32; i++) {
        int f = i * 4 + part;
        acc = fmaf(hl[wave * 132 + f], W2s[f * 16 + col], acc);
    }
    acc += __shfl_xor(acc, 16);
    acc += __shfl_xor(acc, 32);
    if (lane < 16) g2[node * 16 + col] = wv * acc;
}

// ============ aggregate layer 2 (8-deep) ============

__global__ __launch_bounds__(256) void k_agg2(const int* __restrict__ row_ptr,
                                              const int* __restrict__ esrc,
                                              const float* __restrict__ dinv,
                                              const float* __restrict__ g2,
                                              const float* __restrict__ b2,
                                              float* __restrict__ out) {
    int gid = blockIdx.x * 256 + threadIdx.x;
    int node = gid >> 4;
    int f = gid & 15;
    if (node >= N_NODES) return;
    int s = row_ptr[node], t = row_ptr[node + 1];
    float acc = g2[node * 16 + f];
    int e = s;
    for (; e + 7 < t; e += 8) {
        float a0 = g2[esrc[e] * 16 + f],     a1 = g2[esrc[e + 1] * 16 + f];
        float a2 = g2[esrc[e + 2] * 16 + f], a3 = g2[esrc[e + 3] * 16 + f];
        float a4 = g2[esrc[e + 4] * 16 + f], a5 = g2[esrc[e + 5] * 16 + f];
        float a6 = g2[esrc[e + 6] * 16 + f], a7 = g2[esrc[e + 7] * 16 + f];
        acc += a0 + a1 + a2 + a3 + a4 + a5 + a6 + a7;
    }
    for (; e + 3 < t; e += 4) {
        acc += g2[esrc[e] * 16 + f] + g2[esrc[e + 1] * 16 + f]
             + g2[esrc[e + 2] * 16 + f] + g2[esrc[e + 3] * 16 + f];
    }
    for (; e < t; e++) acc += g2[esrc[e] * 16 + f];
    out[node * 16 + f] = fmaf(dinv[node], acc, b2[f]);
}

// ======================= launch =======================

extern "C" void kernel_launch(void* const* d_in, const int* in_sizes, int n_in,
                              void* d_out, int out_size, void* d_ws, size_t ws_size,
                              hipStream_t stream) {
    const float* x   = (const float*)d_in[0];
    const int*   ei  = (const int*)d_in[1];
    const float* W1  = (const float*)d_in[2];
    const float* b1  = (const float*)d_in[3];
    const float* W2  = (const float*)d_in[4];
    const float* b2  = (const float*)d_in[5];
    float* out = (float*)d_out;

    const int* rowi = ei;             // sources
    const int* coli = ei + N_EDGES;   // targets

    char* ws = (char*)d_ws;
    int*          bcnt    = (int*)(ws + 0);
    int*          bbase   = (int*)(ws + 4096);
    int*          bcur    = (int*)(ws + 8192);
    int*          row_ptr = (int*)(ws + 16384);       // 400 KB + 4
    float*        dinv    = (float*)(ws + 524288);    // 400 KB
    unsigned int* ebuf    = (unsigned int*)(ws + 1048576);   // 6.4 MB packed
    int*          esrc    = (int*)(ws + 8388608);     // 6.4 MB
    ushort*       Wt      = (ushort*)(ws + 15728640); // 64 KB
    ushort*       g1      = (ushort*)(ws + 16777216); // 25.6 MB bf16
    float*        g2      = (float*)(ws + 45088768);  // 6.4 MB (live with g1!)

    hipMemsetAsync(bcnt, 0, NB * sizeof(int), stream);

    k_bhist     <<<256, 256, 0, stream>>>(coli, bcnt);
    k_bscan     <<<1, 256, 0, stream>>>(bcnt, bbase, bcur);
    k_binscatter<<<NCHUNK, 256, 0, stream>>>(rowi, coli, bcur, ebuf);
    k_finalize  <<<NB, 256, 0, stream>>>(bbase, ebuf, row_ptr, dinv, esrc);
    k_transW    <<<128, 256, 0, stream>>>(W1, Wt);

    k_gemm1     <<<(N_NODES + 127) / 128, 256, 0, stream>>>(x, Wt, dinv, g1);
    k_agg1g2    <<<N_NODES / 4, 256, 0, stream>>>(row_ptr, esrc, dinv,
                                                  (const unsigned int*)g1, b1, W2, g2);
    k_agg2      <<<(N_NODES * 16 + 255) / 256, 256, 0, stream>>>(row_ptr, esrc, dinv, g2, b2, out);
}

// Round 7
// 358.659 us; speedup vs baseline: 9.4785x; 1.0358x over previous
//
#include <hip/hip_runtime.h>

#define N_NODES 100000
#define N_EDGES 1600000
#define F_IN    256
#define F_HID   128
#define F_OUT   16

#define BSHIFT  9
#define BNODES  512
#define NB      196                 // ceil(100000/512)
#define CHUNK   4096
#define NCHUNK  ((N_EDGES + CHUNK - 1) / CHUNK)   // 391

typedef __attribute__((ext_vector_type(8))) short short8;
typedef __attribute__((ext_vector_type(4))) float float4v;

__device__ __forceinline__ unsigned int bf16_rn(float f) {
    unsigned int u = __float_as_uint(f);
    return (u + 0x7FFFu + ((u >> 16) & 1u)) >> 16;
}
__device__ __forceinline__ unsigned int pk2(float lo, float hi) {
    return bf16_rn(lo) | (bf16_rn(hi) << 16);
}
__device__ __forceinline__ float blo(unsigned int u) { return __uint_as_float(u << 16); }
__device__ __forceinline__ float bhi(unsigned int u) { return __uint_as_float(u & 0xFFFF0000u); }

// ======================= bucketed CSR build =======================

__global__ __launch_bounds__(256) void k_bhist(const int* __restrict__ coli,
                                               int* __restrict__ bcnt) {
    __shared__ int lc[NB];
    int tid = threadIdx.x;
    for (int i = tid; i < NB; i += 256) lc[i] = 0;
    __syncthreads();
    for (int e = blockIdx.x * 256 + tid; e < N_EDGES; e += 256 * 256)
        atomicAdd(&lc[coli[e] >> BSHIFT], 1);
    __syncthreads();
    for (int i = tid; i < NB; i += 256)
        if (lc[i]) atomicAdd(&bcnt[i], lc[i]);
}

__global__ __launch_bounds__(256) void k_bscan(const int* __restrict__ bcnt,
                                               int* __restrict__ bbase,
                                               int* __restrict__ bcur) {
    __shared__ int sc[256];
    int t = threadIdx.x;
    int v = (t < NB) ? bcnt[t] : 0;
    sc[t] = v; __syncthreads();
    for (int off = 1; off < 256; off <<= 1) {
        int x = (t >= off) ? sc[t - off] : 0;
        __syncthreads();
        sc[t] += x;
        __syncthreads();
    }
    if (t < NB) {
        int e = sc[t] - v;
        bbase[t] = e;
        bcur[t]  = e;
    }
    if (t == 0) bbase[NB] = N_EDGES;
}

__global__ __launch_bounds__(256) void k_binscatter(const int* __restrict__ rowi,
                                                    const int* __restrict__ coli,
                                                    int* __restrict__ bcur,
                                                    unsigned int* __restrict__ ebuf) {
    __shared__ int cnt[NB], gbase[NB], run[NB];
    int tid = threadIdx.x;
    int e0 = blockIdx.x * CHUNK;
    for (int i = tid; i < NB; i += 256) { cnt[i] = 0; run[i] = 0; }
    __syncthreads();
    int d[16], s[16];
    #pragma unroll
    for (int i = 0; i < 16; i++) {
        int e = e0 + i * 256 + tid;
        if (e < N_EDGES) {
            d[i] = coli[e]; s[i] = rowi[e];
            atomicAdd(&cnt[d[i] >> BSHIFT], 1);
        } else d[i] = -1;
    }
    __syncthreads();
    for (int i = tid; i < NB; i += 256)
        gbase[i] = cnt[i] ? atomicAdd(&bcur[i], cnt[i]) : 0;
    __syncthreads();
    #pragma unroll
    for (int i = 0; i < 16; i++) {
        if (d[i] >= 0) {
            int b = d[i] >> BSHIFT;
            int off = atomicAdd(&run[b], 1);
            ebuf[gbase[b] + off] = ((unsigned int)(d[i] & 511) << 17) | (unsigned int)s[i];
        }
    }
}

__global__ __launch_bounds__(256) void k_finalize(const int* __restrict__ bbase,
                                                  const unsigned int* __restrict__ ebuf,
                                                  int* __restrict__ row_ptr,
                                                  float* __restrict__ dinv,
                                                  int* __restrict__ esrc) {
    __shared__ int ndeg[BNODES];
    __shared__ int sc[BNODES];
    int tid = threadIdx.x;
    int b   = blockIdx.x;
    int nb0 = b << BSHIFT;
    int ebeg = bbase[b], eend = bbase[b + 1];
    ndeg[tid] = 0; ndeg[tid + 256] = 0;
    __syncthreads();
    for (int e = ebeg + tid; e < eend; e += 256)
        atomicAdd(&ndeg[ebuf[e] >> 17], 1);
    __syncthreads();
    int i0 = tid, i1 = tid + 256;
    sc[i0] = ndeg[i0]; sc[i1] = ndeg[i1];
    __syncthreads();
    for (int off = 1; off < BNODES; off <<= 1) {
        int v0 = (i0 >= off) ? sc[i0 - off] : 0;
        int v1 = (i1 >= off) ? sc[i1 - off] : 0;
        __syncthreads();
        sc[i0] += v0; sc[i1] += v1;
        __syncthreads();
    }
    #pragma unroll
    for (int k = 0; k < 2; k++) {
        int i = tid + k * 256;
        int n = nb0 + i;
        int deg = ndeg[i];
        int excl = sc[i] - deg;
        if (n < N_NODES) {
            row_ptr[n] = ebeg + excl;
            dinv[n]    = rsqrtf(1.0f + (float)deg);
        }
        ndeg[i] = excl;
    }
    if (b == NB - 1 && tid == 0) row_ptr[N_NODES] = N_EDGES;
    __syncthreads();
    for (int e = ebeg + tid; e < eend; e += 256) {
        unsigned int p = ebuf[e];
        int off = atomicAdd(&ndeg[p >> 17], 1);
        esrc[ebeg + off] = (int)(p & 0x1FFFFu);
    }
}

// ============ W1 -> bf16 transposed Wt[col][k] ============

__global__ __launch_bounds__(256) void k_transW(const float* __restrict__ W1,
                                                ushort* __restrict__ Wt) {
    int t = blockIdx.x * 256 + threadIdx.x;
    int c = t & 127, k = t >> 7;
    Wt[c * 256 + k] = (ushort)bf16_rn(W1[k * 128 + c]);
}

// ============ GEMM1 (MFMA bf16, barrier-free K-loop) ============
// Wt (128 cols x 256 k, bf16) staged to LDS ONCE, XOR-swizzled 16B chunks.
// A-fragments loaded directly global->VGPR (fp32->bf16 pack in regs).
// 4 waves x 32 rows = 128 rows/block; no __syncthreads in K-loop.

__global__ __launch_bounds__(256) void k_gemm1(const float* __restrict__ x,
                                               const ushort* __restrict__ Wt,
                                               const float* __restrict__ dinv,
                                               ushort* __restrict__ g1) {
    __shared__ ushort Bl[128 * 256];      // 64 KB, chunk-swizzled
    const int tid = threadIdx.x;
    const int w = tid >> 6;
    const int l = tid & 63;
    const int m = l & 15;       // MFMA m/n index
    const int q = l >> 4;       // quad -> k-chunk
    const int R0 = blockIdx.x * 128;

    // stage Wt: 4096 uint4; chunk j (16B) of col c stored at c*32 + (j^(c&7))
    {
        const uint4* Wg = (const uint4*)Wt;
        uint4* Bl4 = (uint4*)Bl;
        #pragma unroll
        for (int it = 0; it < 16; it++) {
            int i = it * 256 + tid;
            int c = i >> 5, j = i & 31;
            Bl4[c * 32 + (j ^ (c & 7))] = Wg[i];
        }
    }
    __syncthreads();   // the only barrier

    int r0 = R0 + w * 32 + m;      if (r0 > N_NODES - 1) r0 = N_NODES - 1;
    int r1 = R0 + w * 32 + 16 + m; if (r1 > N_NODES - 1) r1 = N_NODES - 1;
    const float* xr0 = &x[(size_t)r0 * F_IN + q * 8];
    const float* xr1 = &x[(size_t)r1 * F_IN + q * 8];
    const short8* Bl8 = (const short8*)Bl;

    float4v acc[2][8];
    #pragma unroll
    for (int i = 0; i < 2; i++)
        #pragma unroll
        for (int j = 0; j < 8; j++) acc[i][j] = (float4v){0.f, 0.f, 0.f, 0.f};

    #pragma unroll 2
    for (int kt = 0; kt < F_IN; kt += 32) {
        float4 a0 = *(const float4*)&xr0[kt];
        float4 a1 = *(const float4*)&xr0[kt + 4];
        float4 b0 = *(const float4*)&xr1[kt];
        float4 b1 = *(const float4*)&xr1[kt + 4];
        short8 af0, af1;
        ((uint*)&af0)[0] = pk2(a0.x, a0.y); ((uint*)&af0)[1] = pk2(a0.z, a0.w);
        ((uint*)&af0)[2] = pk2(a1.x, a1.y); ((uint*)&af0)[3] = pk2(a1.z, a1.w);
        ((uint*)&af1)[0] = pk2(b0.x, b0.y); ((uint*)&af1)[1] = pk2(b0.z, b0.w);
        ((uint*)&af1)[2] = pk2(b1.x, b1.y); ((uint*)&af1)[3] = pk2(b1.z, b1.w);
        int jq = (kt >> 3) + q;    // k-chunk index for this lane
        #pragma unroll
        for (int n = 0; n < 8; n++) {
            int col = n * 16 + m;
            short8 bfr = Bl8[col * 32 + (jq ^ (col & 7))];
            acc[0][n] = __builtin_amdgcn_mfma_f32_16x16x32_bf16(af0, bfr, acc[0][n], 0, 0, 0);
            acc[1][n] = __builtin_amdgcn_mfma_f32_16x16x32_bf16(af1, bfr, acc[1][n], 0, 0, 0);
        }
    }

    // epilogue: C/D layout col=m, row=q*4+reg
    const int rbase = R0 + w * 32 + q * 4;
    float dv0[4], dv1[4];
    #pragma unroll
    for (int r = 0; r < 4; r++) {
        int v0 = rbase + r;      dv0[r] = (v0 < N_NODES) ? dinv[v0] : 0.f;
        int v1 = rbase + 16 + r; dv1[r] = (v1 < N_NODES) ? dinv[v1] : 0.f;
    }
    #pragma unroll
    for (int n = 0; n < 8; n++) {
        #pragma unroll
        for (int r = 0; r < 4; r++) {
            int v0 = rbase + r;
            if (v0 < N_NODES)
                g1[v0 * F_HID + n * 16 + m] = (ushort)bf16_rn(dv0[r] * acc[0][n][r]);
            int v1 = rbase + 16 + r;
            if (v1 < N_NODES)
                g1[v1 * F_HID + n * 16 + m] = (ushort)bf16_rn(dv1[r] * acc[1][n][r]);
        }
    }
}

// ==== fused agg1 + GEMM2, barrier-free: waves fully independent ====
// wave-private LDS strip for the h1 row; only barrier is after W2s stage.

__global__ __launch_bounds__(256) void k_agg1g2(const int* __restrict__ row_ptr,
                                                const int* __restrict__ esrc,
                                                const float* __restrict__ dinv,
                                                const unsigned int* __restrict__ g1,
                                                const float* __restrict__ b1,
                                                const float* __restrict__ W2,
                                                float* __restrict__ g2) {
    __shared__ float hl[4][132];
    __shared__ float W2s[F_HID * F_OUT];
    const int tid  = threadIdx.x;
    const int wave = tid >> 6;
    const int lane = tid & 63;
    const int node = blockIdx.x * 4 + wave;   // 25000*4 == N_NODES exactly

    for (int i = tid; i < F_HID * F_OUT; i += 256) W2s[i] = W2[i];
    __syncthreads();    // only barrier; before any gather work

    int s = row_ptr[node], t = row_ptr[node + 1];
    unsigned int u = g1[node * 64 + lane];     // self-loop
    float ax = blo(u), ay = bhi(u);
    int e = s;
    for (; e + 7 < t; e += 8) {
        int r0 = esrc[e],     r1 = esrc[e + 1], r2 = esrc[e + 2], r3 = esrc[e + 3];
        int r4 = esrc[e + 4], r5 = esrc[e + 5], r6 = esrc[e + 6], r7 = esrc[e + 7];
        unsigned int u0 = g1[r0 * 64 + lane], u1 = g1[r1 * 64 + lane];
        unsigned int u2 = g1[r2 * 64 + lane], u3 = g1[r3 * 64 + lane];
        unsigned int u4 = g1[r4 * 64 + lane], u5 = g1[r5 * 64 + lane];
        unsigned int u6 = g1[r6 * 64 + lane], u7 = g1[r7 * 64 + lane];
        ax += blo(u0) + blo(u1) + blo(u2) + blo(u3)
            + blo(u4) + blo(u5) + blo(u6) + blo(u7);
        ay += bhi(u0) + bhi(u1) + bhi(u2) + bhi(u3)
            + bhi(u4) + bhi(u5) + bhi(u6) + bhi(u7);
    }
    for (; e + 3 < t; e += 4) {
        int r0 = esrc[e], r1 = esrc[e + 1], r2 = esrc[e + 2], r3 = esrc[e + 3];
        unsigned int u0 = g1[r0 * 64 + lane], u1 = g1[r1 * 64 + lane];
        unsigned int u2 = g1[r2 * 64 + lane], u3 = g1[r3 * 64 + lane];
        ax += blo(u0) + blo(u1) + blo(u2) + blo(u3);
        ay += bhi(u0) + bhi(u1) + bhi(u2) + bhi(u3);
    }
    for (; e < t; e++) {
        unsigned int u0 = g1[esrc[e] * 64 + lane];
        ax += blo(u0); ay += bhi(u0);
    }
    float wv = dinv[node];
    float2 bb = ((const float2*)b1)[lane];
    hl[wave][lane * 2]     = fmaxf(fmaf(wv, ax, bb.x), 0.0f);
    hl[wave][lane * 2 + 1] = fmaxf(fmaf(wv, ay, bb.y), 0.0f);
    // NO barrier: hl[wave] written and read only by this wave (lgkmcnt orders)

    const int col = lane & 15, part = lane >> 4;
    float acc = 0.f;
    #pragma unroll
    for (int i = 0; i < 32; i++) {
        int f = i * 4 + part;
        acc = fmaf(hl[wave][f], W2s[f * 16 + col], acc);
    }
    acc += __shfl_xor(acc, 16);
    acc += __shfl_xor(acc, 32);
    if (lane < 16) g2[node * 16 + col] = wv * acc;
}

// ============ aggregate layer 2 (8-deep) ============

__global__ __launch_bounds__(256) void k_agg2(const int* __restrict__ row_ptr,
                                              const int* __restrict__ esrc,
                                              const float* __restrict__ dinv,
                                              const float* __restrict__ g2,
                                              const float* __restrict__ b2,
                                              float* __restrict__ out) {
    int gid = blockIdx.x * 256 + threadIdx.x;
    int node = gid >> 4;
    int f = gid & 15;
    if (node >= N_NODES) return;
    int s = row_ptr[node], t = row_ptr[node + 1];
    float acc = g2[node * 16 + f];
    int e = s;
    for (; e + 7 < t; e += 8) {
        float a0 = g2[esrc[e] * 16 + f],     a1 = g2[esrc[e + 1] * 16 + f];
        float a2 = g2[esrc[e + 2] * 16 + f], a3 = g2[esrc[e + 3] * 16 + f];
        float a4 = g2[esrc[e + 4] * 16 + f], a5 = g2[esrc[e + 5] * 16 + f];
        float a6 = g2[esrc[e + 6] * 16 + f], a7 = g2[esrc[e + 7] * 16 + f];
        acc += a0 + a1 + a2 + a3 + a4 + a5 + a6 + a7;
    }
    for (; e + 3 < t; e += 4) {
        acc += g2[esrc[e] * 16 + f] + g2[esrc[e + 1] * 16 + f]
             + g2[esrc[e + 2] * 16 + f] + g2[esrc[e + 3] * 16 + f];
    }
    for (; e < t; e++) acc += g2[esrc[e] * 16 + f];
    out[node * 16 + f] = fmaf(dinv[node], acc, b2[f]);
}

// ======================= launch =======================

extern "C" void kernel_launch(void* const* d_in, const int* in_sizes, int n_in,
                              void* d_out, int out_size, void* d_ws, size_t ws_size,
                              hipStream_t stream) {
    const float* x   = (const float*)d_in[0];
    const int*   ei  = (const int*)d_in[1];
    const float* W1  = (const float*)d_in[2];
    const float* b1  = (const float*)d_in[3];
    const float* W2  = (const float*)d_in[4];
    const float* b2  = (const float*)d_in[5];
    float* out = (float*)d_out;

    const int* rowi = ei;             // sources
    const int* coli = ei + N_EDGES;   // targets

    char* ws = (char*)d_ws;
    int*          bcnt    = (int*)(ws + 0);
    int*          bbase   = (int*)(ws + 4096);
    int*          bcur    = (int*)(ws + 8192);
    int*          row_ptr = (int*)(ws + 16384);       // 400 KB + 4
    float*        dinv    = (float*)(ws + 524288);    // 400 KB
    unsigned int* ebuf    = (unsigned int*)(ws + 1048576);   // 6.4 MB packed
    int*          esrc    = (int*)(ws + 8388608);     // 6.4 MB
    ushort*       Wt      = (ushort*)(ws + 15728640); // 64 KB
    ushort*       g1      = (ushort*)(ws + 16777216); // 25.6 MB bf16
    float*        g2      = (float*)(ws + 45088768);  // 6.4 MB (live with g1!)

    hipMemsetAsync(bcnt, 0, NB * sizeof(int), stream);

    k_bhist     <<<256, 256, 0, stream>>>(coli, bcnt);
    k_bscan     <<<1, 256, 0, stream>>>(bcnt, bbase, bcur);
    k_binscatter<<<NCHUNK, 256, 0, stream>>>(rowi, coli, bcur, ebuf);
    k_finalize  <<<NB, 256, 0, stream>>>(bbase, ebuf, row_ptr, dinv, esrc);
    k_transW    <<<128, 256, 0, stream>>>(W1, Wt);

    k_gemm1     <<<(N_NODES + 127) / 128, 256, 0, stream>>>(x, Wt, dinv, g1);
    k_agg1g2    <<<N_NODES / 4, 256, 0, stream>>>(row_ptr, esrc, dinv,
                                                  (const unsigned int*)g1, b1, W2, g2);
    k_agg2      <<<(N_NODES * 16 + 255) / 256, 256, 0, stream>>>(row_ptr, esrc, dinv, g2, b2, out);
}

// Round 8
// 328.289 us; speedup vs baseline: 10.3554x; 1.0925x over previous
//
#include <hip/hip_runtime.h>

#define N_NODES 100000
#define N_EDGES 1600000
#define F_IN    256
#define F_HID   128
#define F_OUT   16

#define BSHIFT  9
#define BNODES  512
#define NB      196                 // ceil(100000/512)
#define ECAP    16384               // per-bucket capacity (mean 8163; +90 sigma safe)
#define CHUNK   4096
#define NCHUNK  ((N_EDGES + CHUNK - 1) / CHUNK)   // 391

typedef __attribute__((ext_vector_type(8))) short short8;
typedef __attribute__((ext_vector_type(4))) float float4v;

__device__ __forceinline__ unsigned int bf16_rn(float f) {
    unsigned int u = __float_as_uint(f);
    return (u + 0x7FFFu + ((u >> 16) & 1u)) >> 16;
}
__device__ __forceinline__ unsigned int pk2(float lo, float hi) {
    return bf16_rn(lo) | (bf16_rn(hi) << 16);
}
__device__ __forceinline__ float blo(unsigned int u) { return __uint_as_float(u << 16); }
__device__ __forceinline__ float bhi(unsigned int u) { return __uint_as_float(u & 0xFFFF0000u); }
__device__ __forceinline__ float bfu(unsigned short u) { return __uint_as_float(((unsigned int)u) << 16); }

// ======================= bucketed CSR build (fixed capacity) =======================

__global__ __launch_bounds__(256) void k_binit(int* __restrict__ bcur) {
    int i = threadIdx.x;
    if (i < NB) bcur[i] = i * ECAP;
}

__global__ __launch_bounds__(256) void k_binscatter(const int* __restrict__ rowi,
                                                    const int* __restrict__ coli,
                                                    int* __restrict__ bcur,
                                                    unsigned int* __restrict__ ebuf) {
    __shared__ int cnt[NB], gbase[NB], run[NB];
    int tid = threadIdx.x;
    int e0 = blockIdx.x * CHUNK;
    for (int i = tid; i < NB; i += 256) { cnt[i] = 0; run[i] = 0; }
    __syncthreads();
    int d[16], s[16];
    #pragma unroll
    for (int i = 0; i < 16; i++) {
        int e = e0 + i * 256 + tid;
        if (e < N_EDGES) {
            d[i] = coli[e]; s[i] = rowi[e];
            atomicAdd(&cnt[d[i] >> BSHIFT], 1);
        } else d[i] = -1;
    }
    __syncthreads();
    for (int i = tid; i < NB; i += 256)
        gbase[i] = cnt[i] ? atomicAdd(&bcur[i], cnt[i]) : 0;
    __syncthreads();
    #pragma unroll
    for (int i = 0; i < 16; i++) {
        if (d[i] >= 0) {
            int b = d[i] >> BSHIFT;
            int off = atomicAdd(&run[b], 1);
            ebuf[gbase[b] + off] = ((unsigned int)(d[i] & 511) << 17) | (unsigned int)s[i];
        }
    }
}

__global__ __launch_bounds__(256) void k_finalize(const int* __restrict__ bcur,
                                                  const unsigned int* __restrict__ ebuf,
                                                  int* __restrict__ rp_start,
                                                  int* __restrict__ rp_end,
                                                  float* __restrict__ dinv,
                                                  int* __restrict__ esrc) {
    __shared__ int ndeg[BNODES];
    __shared__ int sc[BNODES];
    int tid = threadIdx.x;
    int b   = blockIdx.x;
    int nb0 = b << BSHIFT;
    int ebeg = b * ECAP, eend = bcur[b];
    ndeg[tid] = 0; ndeg[tid + 256] = 0;
    __syncthreads();
    for (int e = ebeg + tid; e < eend; e += 256)
        atomicAdd(&ndeg[ebuf[e] >> 17], 1);
    __syncthreads();
    int i0 = tid, i1 = tid + 256;
    sc[i0] = ndeg[i0]; sc[i1] = ndeg[i1];
    __syncthreads();
    for (int off = 1; off < BNODES; off <<= 1) {
        int v0 = (i0 >= off) ? sc[i0 - off] : 0;
        int v1 = (i1 >= off) ? sc[i1 - off] : 0;
        __syncthreads();
        sc[i0] += v0; sc[i1] += v1;
        __syncthreads();
    }
    #pragma unroll
    for (int k = 0; k < 2; k++) {
        int i = tid + k * 256;
        int n = nb0 + i;
        int deg = ndeg[i];
        int excl = sc[i] - deg;
        if (n < N_NODES) {
            rp_start[n] = ebeg + excl;
            rp_end[n]   = ebeg + excl + deg;
            dinv[n]     = rsqrtf(1.0f + (float)deg);
        }
        ndeg[i] = excl;
    }
    __syncthreads();
    for (int e = ebeg + tid; e < eend; e += 256) {
        unsigned int p = ebuf[e];
        int off = atomicAdd(&ndeg[p >> 17], 1);
        esrc[ebeg + off] = (int)(p & 0x1FFFFu);
    }
}

// ============ W1 -> bf16 transposed Wt[col][k] ============

__global__ __launch_bounds__(256) void k_transW(const float* __restrict__ W1,
                                                ushort* __restrict__ Wt) {
    int t = blockIdx.x * 256 + threadIdx.x;
    int c = t & 127, k = t >> 7;
    Wt[c * 256 + k] = (ushort)bf16_rn(W1[k * 128 + c]);
}

// ============ GEMM1 (MFMA bf16, barrier-free K-loop) ============

__global__ __launch_bounds__(256) void k_gemm1(const float* __restrict__ x,
                                               const ushort* __restrict__ Wt,
                                               const float* __restrict__ dinv,
                                               ushort* __restrict__ g1) {
    __shared__ ushort Bl[128 * 256];      // 64 KB, chunk-swizzled
    const int tid = threadIdx.x;
    const int w = tid >> 6;
    const int l = tid & 63;
    const int m = l & 15;
    const int q = l >> 4;
    const int R0 = blockIdx.x * 128;

    {
        const uint4* Wg = (const uint4*)Wt;
        uint4* Bl4 = (uint4*)Bl;
        #pragma unroll
        for (int it = 0; it < 16; it++) {
            int i = it * 256 + tid;
            int c = i >> 5, j = i & 31;
            Bl4[c * 32 + (j ^ (c & 7))] = Wg[i];
        }
    }
    __syncthreads();   // the only barrier

    int r0 = R0 + w * 32 + m;      if (r0 > N_NODES - 1) r0 = N_NODES - 1;
    int r1 = R0 + w * 32 + 16 + m; if (r1 > N_NODES - 1) r1 = N_NODES - 1;
    const float* xr0 = &x[(size_t)r0 * F_IN + q * 8];
    const float* xr1 = &x[(size_t)r1 * F_IN + q * 8];
    const short8* Bl8 = (const short8*)Bl;

    float4v acc[2][8];
    #pragma unroll
    for (int i = 0; i < 2; i++)
        #pragma unroll
        for (int j = 0; j < 8; j++) acc[i][j] = (float4v){0.f, 0.f, 0.f, 0.f};

    #pragma unroll 2
    for (int kt = 0; kt < F_IN; kt += 32) {
        float4 a0 = *(const float4*)&xr0[kt];
        float4 a1 = *(const float4*)&xr0[kt + 4];
        float4 b0 = *(const float4*)&xr1[kt];
        float4 b1 = *(const float4*)&xr1[kt + 4];
        short8 af0, af1;
        ((uint*)&af0)[0] = pk2(a0.x, a0.y); ((uint*)&af0)[1] = pk2(a0.z, a0.w);
        ((uint*)&af0)[2] = pk2(a1.x, a1.y); ((uint*)&af0)[3] = pk2(a1.z, a1.w);
        ((uint*)&af1)[0] = pk2(b0.x, b0.y); ((uint*)&af1)[1] = pk2(b0.z, b0.w);
        ((uint*)&af1)[2] = pk2(b1.x, b1.y); ((uint*)&af1)[3] = pk2(b1.z, b1.w);
        int jq = (kt >> 3) + q;
        #pragma unroll
        for (int n = 0; n < 8; n++) {
            int col = n * 16 + m;
            short8 bfr = Bl8[col * 32 + (jq ^ (col & 7))];
            acc[0][n] = __builtin_amdgcn_mfma_f32_16x16x32_bf16(af0, bfr, acc[0][n], 0, 0, 0);
            acc[1][n] = __builtin_amdgcn_mfma_f32_16x16x32_bf16(af1, bfr, acc[1][n], 0, 0, 0);
        }
    }

    const int rbase = R0 + w * 32 + q * 4;
    float dv0[4], dv1[4];
    #pragma unroll
    for (int r = 0; r < 4; r++) {
        int v0 = rbase + r;      dv0[r] = (v0 < N_NODES) ? dinv[v0] : 0.f;
        int v1 = rbase + 16 + r; dv1[r] = (v1 < N_NODES) ? dinv[v1] : 0.f;
    }
    #pragma unroll
    for (int n = 0; n < 8; n++) {
        #pragma unroll
        for (int r = 0; r < 4; r++) {
            int v0 = rbase + r;
            if (v0 < N_NODES)
                g1[v0 * F_HID + n * 16 + m] = (ushort)bf16_rn(dv0[r] * acc[0][n][r]);
            int v1 = rbase + 16 + r;
            if (v1 < N_NODES)
                g1[v1 * F_HID + n * 16 + m] = (ushort)bf16_rn(dv1[r] * acc[1][n][r]);
        }
    }
}

// ==== fused agg1 + GEMM2, ZERO barriers: W2 in registers, 16 nodes/block ====
// g2 output stored as bf16 (3.2 MB -> per-XCD L2 resident for agg2).

__global__ __launch_bounds__(256) void k_agg1g2(const int* __restrict__ rp_start,
                                                const int* __restrict__ rp_end,
                                                const int* __restrict__ esrc,
                                                const float* __restrict__ dinv,
                                                const unsigned int* __restrict__ g1,
                                                const float* __restrict__ b1,
                                                const float* __restrict__ W2,
                                                ushort* __restrict__ g2b) {
    __shared__ float hl[4][132];
    const int tid  = threadIdx.x;
    const int wave = tid >> 6;
    const int lane = tid & 63;
    const int col  = lane & 15, part = lane >> 4;

    // W2 column cache: w2r[i] = W2[(i*4+part)*16 + col] = W2[i*64 + lane] (coalesced)
    float w2r[32];
    #pragma unroll
    for (int i = 0; i < 32; i++) w2r[i] = W2[i * 64 + lane];

    float2 bb = ((const float2*)b1)[lane];

    #pragma unroll 1
    for (int j = 0; j < 4; j++) {
        const int node = blockIdx.x * 16 + j * 4 + wave;   // 6250*16 == N_NODES
        int s = rp_start[node], t = rp_end[node];
        unsigned int u = g1[node * 64 + lane];             // self-loop
        float ax = blo(u), ay = bhi(u);
        int e = s;
        for (; e + 7 < t; e += 8) {
            int r0 = esrc[e],     r1 = esrc[e + 1], r2 = esrc[e + 2], r3 = esrc[e + 3];
            int r4 = esrc[e + 4], r5 = esrc[e + 5], r6 = esrc[e + 6], r7 = esrc[e + 7];
            unsigned int u0 = g1[r0 * 64 + lane], u1 = g1[r1 * 64 + lane];
            unsigned int u2 = g1[r2 * 64 + lane], u3 = g1[r3 * 64 + lane];
            unsigned int u4 = g1[r4 * 64 + lane], u5 = g1[r5 * 64 + lane];
            unsigned int u6 = g1[r6 * 64 + lane], u7 = g1[r7 * 64 + lane];
            ax += blo(u0) + blo(u1) + blo(u2) + blo(u3)
                + blo(u4) + blo(u5) + blo(u6) + blo(u7);
            ay += bhi(u0) + bhi(u1) + bhi(u2) + bhi(u3)
                + bhi(u4) + bhi(u5) + bhi(u6) + bhi(u7);
        }
        for (; e + 3 < t; e += 4) {
            int r0 = esrc[e], r1 = esrc[e + 1], r2 = esrc[e + 2], r3 = esrc[e + 3];
            unsigned int u0 = g1[r0 * 64 + lane], u1 = g1[r1 * 64 + lane];
            unsigned int u2 = g1[r2 * 64 + lane], u3 = g1[r3 * 64 + lane];
            ax += blo(u0) + blo(u1) + blo(u2) + blo(u3);
            ay += bhi(u0) + bhi(u1) + bhi(u2) + bhi(u3);
        }
        for (; e < t; e++) {
            unsigned int u0 = g1[esrc[e] * 64 + lane];
            ax += blo(u0); ay += bhi(u0);
        }
        float wv = dinv[node];
        hl[wave][lane * 2]     = fmaxf(fmaf(wv, ax, bb.x), 0.0f);
        hl[wave][lane * 2 + 1] = fmaxf(fmaf(wv, ay, bb.y), 0.0f);
        // no barrier: wave-private strip, lgkmcnt orders within the wave

        float acc = 0.f;
        #pragma unroll
        for (int i = 0; i < 32; i++)
            acc = fmaf(hl[wave][i * 4 + part], w2r[i], acc);
        acc += __shfl_xor(acc, 16);
        acc += __shfl_xor(acc, 32);
        if (lane < 16) g2b[node * 16 + col] = (ushort)bf16_rn(wv * acc);
    }
}

// ============ aggregate layer 2 (bf16 g2, 8-deep) ============

__global__ __launch_bounds__(256) void k_agg2(const int* __restrict__ rp_start,
                                              const int* __restrict__ rp_end,
                                              const int* __restrict__ esrc,
                                              const float* __restrict__ dinv,
                                              const ushort* __restrict__ g2b,
                                              const float* __restrict__ b2,
                                              float* __restrict__ out) {
    int gid = blockIdx.x * 256 + threadIdx.x;
    int node = gid >> 4;
    int f = gid & 15;
    if (node >= N_NODES) return;
    int s = rp_start[node], t = rp_end[node];
    float acc = bfu(g2b[node * 16 + f]);
    int e = s;
    for (; e + 7 < t; e += 8) {
        float a0 = bfu(g2b[esrc[e] * 16 + f]),     a1 = bfu(g2b[esrc[e + 1] * 16 + f]);
        float a2 = bfu(g2b[esrc[e + 2] * 16 + f]), a3 = bfu(g2b[esrc[e + 3] * 16 + f]);
        float a4 = bfu(g2b[esrc[e + 4] * 16 + f]), a5 = bfu(g2b[esrc[e + 5] * 16 + f]);
        float a6 = bfu(g2b[esrc[e + 6] * 16 + f]), a7 = bfu(g2b[esrc[e + 7] * 16 + f]);
        acc += a0 + a1 + a2 + a3 + a4 + a5 + a6 + a7;
    }
    for (; e + 3 < t; e += 4) {
        acc += bfu(g2b[esrc[e] * 16 + f]) + bfu(g2b[esrc[e + 1] * 16 + f])
             + bfu(g2b[esrc[e + 2] * 16 + f]) + bfu(g2b[esrc[e + 3] * 16 + f]);
    }
    for (; e < t; e++) acc += bfu(g2b[esrc[e] * 16 + f]);
    out[node * 16 + f] = fmaf(dinv[node], acc, b2[f]);
}

// ======================= launch =======================

extern "C" void kernel_launch(void* const* d_in, const int* in_sizes, int n_in,
                              void* d_out, int out_size, void* d_ws, size_t ws_size,
                              hipStream_t stream) {
    const float* x   = (const float*)d_in[0];
    const int*   ei  = (const int*)d_in[1];
    const float* W1  = (const float*)d_in[2];
    const float* b1  = (const float*)d_in[3];
    const float* W2  = (const float*)d_in[4];
    const float* b2  = (const float*)d_in[5];
    float* out = (float*)d_out;

    const int* rowi = ei;             // sources
    const int* coli = ei + N_EDGES;   // targets

    char* ws = (char*)d_ws;
    int*          bcur     = (int*)(ws + 0);             // 784 B
    int*          rp_start = (int*)(ws + 8192);          // 400 KB
    int*          rp_end   = (int*)(ws + 524288);        // 400 KB
    float*        dinv     = (float*)(ws + 1048576);     // 400 KB
    unsigned int* ebuf     = (unsigned int*)(ws + 2097152);   // 12.85 MB (196*16384*4)
    int*          esrc     = (int*)(ws + 16777216);      // 12.85 MB
    ushort*       Wt       = (ushort*)(ws + 31457280);   // 64 KB
    ushort*       g1       = (ushort*)(ws + 33554432);   // 25.6 MB bf16
    ushort*       g2b      = (ushort*)(ws + 62914560);   // 3.2 MB bf16

    k_binit     <<<1, 256, 0, stream>>>(bcur);
    k_binscatter<<<NCHUNK, 256, 0, stream>>>(rowi, coli, bcur, ebuf);
    k_finalize  <<<NB, 256, 0, stream>>>(bcur, ebuf, rp_start, rp_end, dinv, esrc);
    k_transW    <<<128, 256, 0, stream>>>(W1, Wt);

    k_gemm1     <<<(N_NODES + 127) / 128, 256, 0, stream>>>(x, Wt, dinv, g1);
    k_agg1g2    <<<N_NODES / 16, 256, 0, stream>>>(rp_start, rp_end, esrc, dinv,
                                                   (const unsigned int*)g1, b1, W2, g2b);
    k_agg2      <<<(N_NODES * 16 + 255) / 256, 256, 0, stream>>>(rp_start, rp_end, esrc,
                                                                 dinv, g2b, b2, out);
}